// Round 1
// baseline (19388.115 us; speedup 1.0000x reference)
//
#include <hip/hip_runtime.h>
#include <math.h>

#define NB 128
#define NR 32

static constexpr float CUTOFF_F   = 10.0f;
static constexpr float RBF_STEP   = 10.0f / 31.0f;
static constexpr float RBF_COEFF  = -4.805f;          // -0.5/step^2 = -0.5*3.1^2
static constexpr float LOG2_F     = 0.69314718055994531f;
static constexpr float PI_OVER_CUT = 0.314159265358979f; // pi/10

__device__ __forceinline__ float ssp_f(float v) {
    // softplus(v) - log(2), numerically stable
    float a = fabsf(v);
    return fmaxf(v, 0.0f) + log1pf(expf(-a)) - LOG2_F;
}
__device__ __forceinline__ float silu_f(float v) {
    return v / (1.0f + expf(-v));
}

// ---------------------------------------------------------------------------
// Edge prep: distances, cosine cutoff, and stream-compaction of active edges
// (rcut == 0 for d >= CUTOFF -> those edges contribute exactly 0 downstream).
// ---------------------------------------------------------------------------
__global__ void edge_prep(const float* __restrict__ pos,
                          const int* __restrict__ idx_i,
                          const int* __restrict__ idx_j,
                          float* __restrict__ d_ij,
                          float* __restrict__ rcut,
                          int* __restrict__ active,
                          int* __restrict__ count,
                          int E) {
    int e = blockIdx.x * blockDim.x + threadIdx.x;
    if (e >= E) return;
    int a = idx_i[e], b = idx_j[e];
    float dx = pos[a * 3 + 0] - pos[b * 3 + 0];
    float dy = pos[a * 3 + 1] - pos[b * 3 + 1];
    float dz = pos[a * 3 + 2] - pos[b * 3 + 2];
    float d = sqrtf(dx * dx + dy * dy + dz * dz);
    d_ij[e] = d;
    float rc = 0.0f;
    bool act = (d < CUTOFF_F);
    if (act) rc = 0.5f * (cosf(d * PI_OVER_CUT) + 1.0f);
    rcut[e] = rc;
    if (act) {
        int p = atomicAdd(count, 1);
        active[p] = e;
    }
}

// ---------------------------------------------------------------------------
// x = ele_emb[z] + res_emb[z_res]
// ---------------------------------------------------------------------------
__global__ void atom_embed(const int* __restrict__ z,
                           const int* __restrict__ z_res,
                           const float* __restrict__ ele_emb,
                           const float* __restrict__ res_emb,
                           float* __restrict__ x, int N) {
    int t = blockIdx.x * blockDim.x + threadIdx.x;
    if (t >= N * NB) return;
    int n = t >> 7, c = t & 127;
    x[t] = ele_emb[z[n] * NB + c] + res_emb[z_res[n] * NB + c];
}

// ---------------------------------------------------------------------------
// xf = x @ W  (128x128, no bias).  8 atoms per 128-thread block.
// ---------------------------------------------------------------------------
__global__ __launch_bounds__(128) void node_in2f(const float* __restrict__ x,
                                                 const float* __restrict__ W,
                                                 float* __restrict__ xf, int N) {
    int a0 = blockIdx.x * 8;
    int f = threadIdx.x;
    __shared__ float rows[8][NB];
#pragma unroll
    for (int a = 0; a < 8; a++) {
        int n = a0 + a;
        rows[a][f] = (n < N) ? x[n * NB + f] : 0.0f;
    }
    __syncthreads();
    float acc[8] = {0, 0, 0, 0, 0, 0, 0, 0};
    for (int k4 = 0; k4 < 32; k4++) {
        float w0 = W[(4 * k4 + 0) * NB + f];
        float w1 = W[(4 * k4 + 1) * NB + f];
        float w2 = W[(4 * k4 + 2) * NB + f];
        float w3 = W[(4 * k4 + 3) * NB + f];
#pragma unroll
        for (int a = 0; a < 8; a++) {
            float4 r = *(const float4*)&rows[a][4 * k4];
            acc[a] += r.x * w0 + r.y * w1 + r.z * w2 + r.w * w3;
        }
    }
#pragma unroll
    for (int a = 0; a < 8; a++) {
        int n = a0 + a;
        if (n < N) xf[n * NB + f] = acc[a];
    }
}

// ---------------------------------------------------------------------------
// x += ssp(agg @ W1 + b1) @ W2 + b2.   8 atoms per 128-thread block.
// ---------------------------------------------------------------------------
__global__ __launch_bounds__(128) void node_out(const float* __restrict__ agg,
                                                const float* __restrict__ W1,
                                                const float* __restrict__ b1,
                                                const float* __restrict__ W2,
                                                const float* __restrict__ b2,
                                                float* __restrict__ x, int N) {
    int a0 = blockIdx.x * 8;
    int f = threadIdx.x;
    __shared__ float rows[8][NB];
    __shared__ float t1s[8][NB];
#pragma unroll
    for (int a = 0; a < 8; a++) {
        int n = a0 + a;
        rows[a][f] = (n < N) ? agg[n * NB + f] : 0.0f;
    }
    __syncthreads();
    float acc[8];
    float bb = b1[f];
#pragma unroll
    for (int a = 0; a < 8; a++) acc[a] = bb;
    for (int k4 = 0; k4 < 32; k4++) {
        float w0 = W1[(4 * k4 + 0) * NB + f];
        float w1 = W1[(4 * k4 + 1) * NB + f];
        float w2 = W1[(4 * k4 + 2) * NB + f];
        float w3 = W1[(4 * k4 + 3) * NB + f];
#pragma unroll
        for (int a = 0; a < 8; a++) {
            float4 r = *(const float4*)&rows[a][4 * k4];
            acc[a] += r.x * w0 + r.y * w1 + r.z * w2 + r.w * w3;
        }
    }
#pragma unroll
    for (int a = 0; a < 8; a++) t1s[a][f] = ssp_f(acc[a]);
    __syncthreads();
    float bb2 = b2[f];
#pragma unroll
    for (int a = 0; a < 8; a++) acc[a] = bb2;
    for (int k4 = 0; k4 < 32; k4++) {
        float w0 = W2[(4 * k4 + 0) * NB + f];
        float w1 = W2[(4 * k4 + 1) * NB + f];
        float w2 = W2[(4 * k4 + 2) * NB + f];
        float w3 = W2[(4 * k4 + 3) * NB + f];
#pragma unroll
        for (int a = 0; a < 8; a++) {
            float4 r = *(const float4*)&t1s[a][4 * k4];
            acc[a] += r.x * w0 + r.y * w1 + r.z * w2 + r.w * w3;
        }
    }
#pragma unroll
    for (int a = 0; a < 8; a++) {
        int n = a0 + a;
        if (n < N) x[n * NB + f] += acc[a];
    }
}

// ---------------------------------------------------------------------------
// Fused per-edge filter + gather + scatter for one interaction.
// Tile = 64 active edges per 256-thread block.
//   A: f_ij tile (recomputed RBF + edge_emb)     -> LDS [64][33]
//   B: hidden = ssp(f_ij@W1+b1), stored hidT[k][e] -> LDS [128][68]
//   C: Wij = (hidden@W2+b2)*rcut; x_ij = xf[idx_j]*Wij; atomicAdd agg[idx_i]
// ---------------------------------------------------------------------------
__global__ __launch_bounds__(256) void edge_fused(
    const float* __restrict__ d_ij, const float* __restrict__ rcut,
    const int* __restrict__ active, const int* __restrict__ count,
    const int* __restrict__ idx_i, const int* __restrict__ idx_j,
    const int* __restrict__ edge_attr, const float* __restrict__ edge_emb,
    const float* __restrict__ W1, const float* __restrict__ b1,
    const float* __restrict__ W2, const float* __restrict__ b2,
    const float* __restrict__ xf, float* __restrict__ agg) {
    __shared__ float f_tile[64][NR + 1];   // +1 pad: kills 16-way bank conflict on [e][r] reads
    __shared__ float hidT[NB][68];         // hidT[k][e]; 68 keeps float4 rows 16B-aligned

    int cnt = *count;
    int base = blockIdx.x * 64;
    if (base >= cnt) return;
    int t = threadIdx.x;

    // ---- Stage A: RBF tile ----
    {
        int e_loc = t >> 2;
        int r0 = (t & 3) * 8;
        int ei = base + e_loc;
        if (ei < cnt) {
            int e = active[ei];
            float d = d_ij[e];
            int attr = edge_attr[e];
#pragma unroll
            for (int j = 0; j < 8; j++) {
                int r = r0 + j;
                float off = (float)r * RBF_STEP;
                float dd = d - off;
                f_tile[e_loc][r] = expf(RBF_COEFF * dd * dd) + edge_emb[attr * NR + r];
            }
        } else {
#pragma unroll
            for (int j = 0; j < 8; j++) f_tile[e_loc][r0 + j] = 0.0f;
        }
    }
    __syncthreads();

    // ---- Stage B: hidden = ssp(f_ij @ W1 + b1), transposed into LDS ----
    {
        int e_loc = t >> 2;
        int f0 = (t & 3) * 32;
        float acc[32];
#pragma unroll
        for (int j = 0; j < 32; j++) acc[j] = b1[f0 + j];
        for (int r = 0; r < NR; r++) {
            float fv = f_tile[e_loc][r];
            const float4* Wr = (const float4*)(W1 + r * NB + f0);
#pragma unroll
            for (int j4 = 0; j4 < 8; j4++) {
                float4 w = Wr[j4];
                acc[4 * j4 + 0] += fv * w.x;
                acc[4 * j4 + 1] += fv * w.y;
                acc[4 * j4 + 2] += fv * w.z;
                acc[4 * j4 + 3] += fv * w.w;
            }
        }
#pragma unroll
        for (int j = 0; j < 32; j++) hidT[f0 + j][e_loc] = ssp_f(acc[j]);
    }
    __syncthreads();

    // ---- Stage C: Wij = hidden@W2 + b2, times rcut; gather xf, scatter agg ----
    {
        int f_grp = t & 15;
        int e_grp = t >> 4;
        int f0 = f_grp * 8;
        int e0 = e_grp * 4;
        float4 bb0 = *(const float4*)(b2 + f0);
        float4 bb1 = *(const float4*)(b2 + f0 + 4);
        float acc[4][8];
#pragma unroll
        for (int e = 0; e < 4; e++) {
            acc[e][0] = bb0.x; acc[e][1] = bb0.y; acc[e][2] = bb0.z; acc[e][3] = bb0.w;
            acc[e][4] = bb1.x; acc[e][5] = bb1.y; acc[e][6] = bb1.z; acc[e][7] = bb1.w;
        }
        for (int k = 0; k < NB; k++) {
            float4 h4 = *(const float4*)&hidT[k][e0];
            const float4* Wk = (const float4*)(W2 + k * NB + f0);
            float4 w0 = Wk[0];
            float4 w1 = Wk[1];
            float hv[4] = {h4.x, h4.y, h4.z, h4.w};
#pragma unroll
            for (int e = 0; e < 4; e++) {
                float he = hv[e];
                acc[e][0] += he * w0.x; acc[e][1] += he * w0.y;
                acc[e][2] += he * w0.z; acc[e][3] += he * w0.w;
                acc[e][4] += he * w1.x; acc[e][5] += he * w1.y;
                acc[e][6] += he * w1.z; acc[e][7] += he * w1.w;
            }
        }
#pragma unroll
        for (int e = 0; e < 4; e++) {
            int ei = base + e0 + e;
            if (ei >= cnt) continue;
            int edge = active[ei];
            float rc = rcut[edge];
            int jn = idx_j[edge];
            int in_ = idx_i[edge];
            const float4* xj = (const float4*)(xf + (size_t)jn * NB + f0);
            float4 x0 = xj[0];
            float4 x1 = xj[1];
            float* dst = agg + (size_t)in_ * NB + f0;
            atomicAdd(dst + 0, acc[e][0] * rc * x0.x);
            atomicAdd(dst + 1, acc[e][1] * rc * x0.y);
            atomicAdd(dst + 2, acc[e][2] * rc * x0.z);
            atomicAdd(dst + 3, acc[e][3] * rc * x0.w);
            atomicAdd(dst + 4, acc[e][4] * rc * x1.x);
            atomicAdd(dst + 5, acc[e][5] * rc * x1.y);
            atomicAdd(dst + 6, acc[e][6] * rc * x1.z);
            atomicAdd(dst + 7, acc[e][7] * rc * x1.w);
        }
    }
}

// ---------------------------------------------------------------------------
// Head: L2-normalize, silu->W1->silu->W2, segment-sum into out[batch].
// 8 atoms per 128-thread block.
// ---------------------------------------------------------------------------
__global__ __launch_bounds__(128) void head_k(const float* __restrict__ x,
                                              const int* __restrict__ batch,
                                              const float* __restrict__ W1,
                                              const float* __restrict__ b1,
                                              const float* __restrict__ W2,
                                              float* __restrict__ out, int N) {
    int a0 = blockIdx.x * 8;
    int f = threadIdx.x;
    __shared__ float rows[8][NB];
    __shared__ float red[NB][9];  // pad 9 to spread banks
    __shared__ float srow[8][NB];
#pragma unroll
    for (int a = 0; a < 8; a++) {
        int n = a0 + a;
        rows[a][f] = (n < N) ? x[n * NB + f] : 0.0f;
    }
    __syncthreads();
#pragma unroll
    for (int a = 0; a < 8; a++) red[f][a] = rows[a][f] * rows[a][f];
    __syncthreads();
    for (int s = 64; s >= 1; s >>= 1) {
        if (f < s) {
#pragma unroll
            for (int a = 0; a < 8; a++) red[f][a] += red[f + s][a];
        }
        __syncthreads();
    }
    float nrm[8];
#pragma unroll
    for (int a = 0; a < 8; a++) nrm[a] = fmaxf(sqrtf(red[0][a]), 1e-12f);
#pragma unroll
    for (int a = 0; a < 8; a++) {
        float hv = rows[a][f] / nrm[a];
        srow[a][f] = silu_f(hv);
    }
    __syncthreads();
    float acc[8];
    float bb = b1[f];
#pragma unroll
    for (int a = 0; a < 8; a++) acc[a] = bb;
    for (int k4 = 0; k4 < 32; k4++) {
        float w0 = W1[(4 * k4 + 0) * NB + f];
        float w1 = W1[(4 * k4 + 1) * NB + f];
        float w2 = W1[(4 * k4 + 2) * NB + f];
        float w3 = W1[(4 * k4 + 3) * NB + f];
#pragma unroll
        for (int a = 0; a < 8; a++) {
            float4 r = *(const float4*)&srow[a][4 * k4];
            acc[a] += r.x * w0 + r.y * w1 + r.z * w2 + r.w * w3;
        }
    }
    float w2v = W2[f];
#pragma unroll
    for (int a = 0; a < 8; a++) red[f][a] = silu_f(acc[a]) * w2v;
    __syncthreads();
    for (int s = 64; s >= 1; s >>= 1) {
        if (f < s) {
#pragma unroll
            for (int a = 0; a < 8; a++) red[f][a] += red[f + s][a];
        }
        __syncthreads();
    }
    if (f == 0) {
#pragma unroll
        for (int a = 0; a < 8; a++) {
            int n = a0 + a;
            if (n < N) atomicAdd(&out[batch[n]], red[0][a]);
        }
    }
}

// ---------------------------------------------------------------------------
extern "C" void kernel_launch(void* const* d_in, const int* in_sizes, int n_in,
                              void* d_out, int out_size, void* d_ws, size_t ws_size,
                              hipStream_t stream) {
    const int*   z        = (const int*)d_in[0];
    const int*   z_res    = (const int*)d_in[1];
    const float* pos      = (const float*)d_in[2];
    const int*   idx_i    = (const int*)d_in[3];
    const int*   idx_j    = (const int*)d_in[4];
    const int*   edge_attr= (const int*)d_in[5];
    const int*   batch    = (const int*)d_in[6];
    const float* ele_emb  = (const float*)d_in[7];
    const float* res_emb  = (const float*)d_in[8];
    const float* edge_emb = (const float*)d_in[9];
    const float* in2f_W   = (const float*)d_in[10];
    const float* filt_W1  = (const float*)d_in[11];
    const float* filt_b1  = (const float*)d_in[12];
    const float* filt_W2  = (const float*)d_in[13];
    const float* filt_b2  = (const float*)d_in[14];
    const float* f2out_W1 = (const float*)d_in[15];
    const float* f2out_b1 = (const float*)d_in[16];
    const float* f2out_W2 = (const float*)d_in[17];
    const float* f2out_b2 = (const float*)d_in[18];
    const float* head_W1  = (const float*)d_in[19];
    const float* head_b1  = (const float*)d_in[20];
    const float* head_W2  = (const float*)d_in[21];

    const int N = in_sizes[0];
    const int E = in_sizes[3];

    // workspace carve (256B aligned)
    char* p = (char*)d_ws;
    size_t off = 0;
    auto carve = [&](size_t bytes) -> void* {
        void* q = p + off;
        off = (off + bytes + 255) & ~(size_t)255;
        return q;
    };
    float* d_d    = (float*)carve((size_t)E * 4);
    float* d_rc   = (float*)carve((size_t)E * 4);
    int*   active = (int*)carve((size_t)E * 4);
    int*   count  = (int*)carve(256);
    float* x_buf  = (float*)carve((size_t)N * NB * 4);
    float* xf_buf = (float*)carve((size_t)N * NB * 4);
    float* agg    = (float*)carve((size_t)N * NB * 4);
    (void)ws_size;

    hipMemsetAsync(count, 0, sizeof(int), stream);
    edge_prep<<<(E + 255) / 256, 256, 0, stream>>>(pos, idx_i, idx_j, d_d, d_rc, active, count, E);
    atom_embed<<<(N * NB + 255) / 256, 256, 0, stream>>>(z, z_res, ele_emb, res_emb, x_buf, N);

    int nblk_atom = (N + 7) / 8;
    int nblk_edge = (E + 63) / 64;
    for (int i = 0; i < 6; i++) {
        node_in2f<<<nblk_atom, 128, 0, stream>>>(x_buf, in2f_W + (size_t)i * NB * NB, xf_buf, N);
        hipMemsetAsync(agg, 0, (size_t)N * NB * 4, stream);
        edge_fused<<<nblk_edge, 256, 0, stream>>>(
            d_d, d_rc, active, count, idx_i, idx_j, edge_attr, edge_emb,
            filt_W1 + (size_t)i * NR * NB, filt_b1 + (size_t)i * NB,
            filt_W2 + (size_t)i * NB * NB, filt_b2 + (size_t)i * NB,
            xf_buf, agg);
        node_out<<<nblk_atom, 128, 0, stream>>>(
            agg, f2out_W1 + (size_t)i * NB * NB, f2out_b1 + (size_t)i * NB,
            f2out_W2 + (size_t)i * NB * NB, f2out_b2 + (size_t)i * NB, x_buf, N);
    }

    hipMemsetAsync(d_out, 0, (size_t)out_size * sizeof(float), stream);
    head_k<<<nblk_atom, 128, 0, stream>>>(x_buf, batch, head_W1, head_b1, head_W2,
                                          (float*)d_out, N);
}

// Round 2
// 4604.253 us; speedup vs baseline: 4.2109x; 4.2109x over previous
//
#include <hip/hip_runtime.h>
#include <hip/hip_bf16.h>
#include <math.h>

#define NB 128
#define NR 32
#define EPAD 40    // fA row stride in shorts (80B rows -> bank-spread)
#define HPAD 136   // H/XA row stride in shorts (272B rows -> bank-spread)

static constexpr float CUTOFF_F    = 10.0f;
static constexpr float RBF_STEP    = 10.0f / 31.0f;
static constexpr float RBF_COEFF   = -4.805f;           // -0.5/(10/31)^2
static constexpr float LOG2_F      = 0.69314718055994531f;
static constexpr float PI_OVER_CUT = 0.314159265358979f;

typedef __attribute__((ext_vector_type(8))) short bf16x8;
typedef __attribute__((ext_vector_type(4))) float f32x4;

__device__ __forceinline__ short f2bs(float x) {
    __hip_bfloat16 h = __float2bfloat16(x);   // RNE
    return *reinterpret_cast<short*>(&h);
}
__device__ __forceinline__ float ssp_f(float v) {
    // softplus(v) - log(2), stable, fast intrinsics (fp32-accurate enough)
    return fmaxf(v, 0.0f) + __logf(1.0f + __expf(-fabsf(v))) - LOG2_F;
}
__device__ __forceinline__ float silu_f(float v) {
    return v / (1.0f + __expf(-v));
}

// ---------------------------------------------------------------------------
// Weight prep: dst[b][c][r] = bf16(src[b][r][c])   (transpose + cvt)
// ---------------------------------------------------------------------------
__global__ void transpose_cvt(const float* __restrict__ src, short* __restrict__ dst,
                              int R, int C, int total) {
    int t = blockIdx.x * blockDim.x + threadIdx.x;
    if (t >= total) return;
    int rc = R * C;
    int b = t / rc;
    int rem = t - b * rc;
    int c = rem / R;
    int r = rem - c * R;
    dst[t] = f2bs(src[(size_t)b * rc + (size_t)r * C + c]);
}

// ---------------------------------------------------------------------------
// Edge prep: distances, cosine cutoff, stream-compaction of active edges.
// ---------------------------------------------------------------------------
__global__ void edge_prep(const float* __restrict__ pos,
                          const int* __restrict__ idx_i,
                          const int* __restrict__ idx_j,
                          float* __restrict__ d_ij,
                          float* __restrict__ rcut,
                          int* __restrict__ active,
                          int* __restrict__ count,
                          int E) {
    int e = blockIdx.x * blockDim.x + threadIdx.x;
    if (e >= E) return;
    int a = idx_i[e], b = idx_j[e];
    float dx = pos[a * 3 + 0] - pos[b * 3 + 0];
    float dy = pos[a * 3 + 1] - pos[b * 3 + 1];
    float dz = pos[a * 3 + 2] - pos[b * 3 + 2];
    float d = sqrtf(dx * dx + dy * dy + dz * dz);
    d_ij[e] = d;
    float rc = 0.0f;
    bool act = (d < CUTOFF_F);
    if (act) rc = 0.5f * (cosf(d * PI_OVER_CUT) + 1.0f);
    rcut[e] = rc;
    if (act) {
        int p = atomicAdd(count, 1);
        active[p] = e;
    }
}

// ---------------------------------------------------------------------------
// x = ele_emb[z] + res_emb[z_res]
// ---------------------------------------------------------------------------
__global__ void atom_embed(const int* __restrict__ z,
                           const int* __restrict__ z_res,
                           const float* __restrict__ ele_emb,
                           const float* __restrict__ res_emb,
                           float* __restrict__ x, int N) {
    int t = blockIdx.x * blockDim.x + threadIdx.x;
    if (t >= N * NB) return;
    int n = t >> 7, c = t & 127;
    x[t] = ele_emb[z[n] * NB + c] + res_emb[z_res[n] * NB + c];
}

// ---------------------------------------------------------------------------
// out[64xNB] = in[64xNB] @ W  via MFMA (bf16 in, fp32 acc). 4 waves/block,
// wave w owns M-tile w. WT is bf16 [NB][NB] transposed (WT[n][k]).
// ---------------------------------------------------------------------------
__global__ __launch_bounds__(256, 4) void node_in2f_mfma(
    const float* __restrict__ x, const short* __restrict__ WT,
    float* __restrict__ out, int N) {
    __shared__ __align__(16) short XA[64 * HPAD];
    int a0 = blockIdx.x * 64;
    int t = threadIdx.x;
    // stage x -> bf16 LDS
#pragma unroll
    for (int c = 0; c < 4; c++) {
        int chunk = t + c * 256;            // 1024 chunks of 8
        int row = chunk >> 4;
        int col = (chunk & 15) * 8;
        short v[8];
        if (a0 + row < N) {
            const float* src = x + (size_t)(a0 + row) * NB + col;
            float4 f0 = *(const float4*)src;
            float4 f1 = *(const float4*)(src + 4);
            v[0] = f2bs(f0.x); v[1] = f2bs(f0.y); v[2] = f2bs(f0.z); v[3] = f2bs(f0.w);
            v[4] = f2bs(f1.x); v[5] = f2bs(f1.y); v[6] = f2bs(f1.z); v[7] = f2bs(f1.w);
        } else {
#pragma unroll
            for (int j = 0; j < 8; j++) v[j] = 0;
        }
        *(bf16x8*)&XA[row * HPAD + col] = *(bf16x8*)v;
    }
    __syncthreads();

    int wid = t >> 6, lane = t & 63;
    int quad = lane >> 4, col = lane & 15;
    int mrow = wid * 16 + col;

    f32x4 acc[8] = {};
#pragma unroll
    for (int kt = 0; kt < 4; kt++) {
        bf16x8 a = *(bf16x8*)&XA[mrow * HPAD + kt * 32 + quad * 8];
#pragma unroll
        for (int nt = 0; nt < 8; nt++) {
            bf16x8 b = *(const bf16x8*)&WT[(nt * 16 + col) * NB + kt * 32 + quad * 8];
            acc[nt] = __builtin_amdgcn_mfma_f32_16x16x32_bf16(a, b, acc[nt], 0, 0, 0);
        }
    }
#pragma unroll
    for (int nt = 0; nt < 8; nt++) {
        int n = nt * 16 + col;
#pragma unroll
        for (int r = 0; r < 4; r++) {
            int m = wid * 16 + quad * 4 + r;
            if (a0 + m < N) out[(size_t)(a0 + m) * NB + n] = acc[nt][r];
        }
    }
}

// ---------------------------------------------------------------------------
// x += ssp(agg @ W1 + b1) @ W2 + b2   (bf16 MFMA both GEMMs)
// ---------------------------------------------------------------------------
__global__ __launch_bounds__(256, 4) void node_out_mfma(
    const float* __restrict__ agg,
    const short* __restrict__ W1T, const float* __restrict__ b1,
    const short* __restrict__ W2T, const float* __restrict__ b2,
    float* __restrict__ x, int N) {
    __shared__ __align__(16) short XA[64 * HPAD];
    __shared__ __align__(16) short H[64 * HPAD];
    int a0 = blockIdx.x * 64;
    int t = threadIdx.x;
#pragma unroll
    for (int c = 0; c < 4; c++) {
        int chunk = t + c * 256;
        int row = chunk >> 4;
        int col = (chunk & 15) * 8;
        short v[8];
        if (a0 + row < N) {
            const float* src = agg + (size_t)(a0 + row) * NB + col;
            float4 f0 = *(const float4*)src;
            float4 f1 = *(const float4*)(src + 4);
            v[0] = f2bs(f0.x); v[1] = f2bs(f0.y); v[2] = f2bs(f0.z); v[3] = f2bs(f0.w);
            v[4] = f2bs(f1.x); v[5] = f2bs(f1.y); v[6] = f2bs(f1.z); v[7] = f2bs(f1.w);
        } else {
#pragma unroll
            for (int j = 0; j < 8; j++) v[j] = 0;
        }
        *(bf16x8*)&XA[row * HPAD + col] = *(bf16x8*)v;
    }
    __syncthreads();

    int wid = t >> 6, lane = t & 63;
    int quad = lane >> 4, col = lane & 15;
    int mrow = wid * 16 + col;

    // GEMM1 + ssp -> H
    {
        f32x4 acc[8] = {};
#pragma unroll
        for (int kt = 0; kt < 4; kt++) {
            bf16x8 a = *(bf16x8*)&XA[mrow * HPAD + kt * 32 + quad * 8];
#pragma unroll
            for (int nt = 0; nt < 8; nt++) {
                bf16x8 b = *(const bf16x8*)&W1T[(nt * 16 + col) * NB + kt * 32 + quad * 8];
                acc[nt] = __builtin_amdgcn_mfma_f32_16x16x32_bf16(a, b, acc[nt], 0, 0, 0);
            }
        }
#pragma unroll
        for (int nt = 0; nt < 8; nt++) {
            int n = nt * 16 + col;
            float bias = b1[n];
#pragma unroll
            for (int r = 0; r < 4; r++) {
                int m = wid * 16 + quad * 4 + r;
                H[m * HPAD + n] = f2bs(ssp_f(acc[nt][r] + bias));
            }
        }
    }
    __syncthreads();

    // GEMM2 + residual add
    {
        f32x4 acc[8] = {};
#pragma unroll
        for (int kt = 0; kt < 4; kt++) {
            bf16x8 a = *(bf16x8*)&H[mrow * HPAD + kt * 32 + quad * 8];
#pragma unroll
            for (int nt = 0; nt < 8; nt++) {
                bf16x8 b = *(const bf16x8*)&W2T[(nt * 16 + col) * NB + kt * 32 + quad * 8];
                acc[nt] = __builtin_amdgcn_mfma_f32_16x16x32_bf16(a, b, acc[nt], 0, 0, 0);
            }
        }
#pragma unroll
        for (int nt = 0; nt < 8; nt++) {
            int n = nt * 16 + col;
            float bias = b2[n];
#pragma unroll
            for (int r = 0; r < 4; r++) {
                int m = wid * 16 + quad * 4 + r;
                if (a0 + m < N) {
                    size_t o = (size_t)(a0 + m) * NB + n;
                    x[o] += acc[nt][r] + bias;
                }
            }
        }
    }
}

// ---------------------------------------------------------------------------
// Fused edge filter (MFMA) + gather + scatter. 64 active edges per block.
// ---------------------------------------------------------------------------
__global__ __launch_bounds__(256, 4) void edge_fused_mfma(
    const float* __restrict__ d_ij, const float* __restrict__ rcut,
    const int* __restrict__ active, const int* __restrict__ count,
    const int* __restrict__ idx_i, const int* __restrict__ idx_j,
    const int* __restrict__ edge_attr, const float* __restrict__ edge_emb,
    const short* __restrict__ W1T, const float* __restrict__ b1,
    const short* __restrict__ W2T, const float* __restrict__ b2,
    const float* __restrict__ xf, float* __restrict__ agg) {
    __shared__ __align__(16) short fA[64 * EPAD];
    __shared__ __align__(16) short H[64 * HPAD];
    __shared__ float sRC[64];
    __shared__ int sI[64], sJ[64];

    int cnt = *count;
    int base = blockIdx.x * 64;
    if (base >= cnt) return;
    int t = threadIdx.x;

    if (t < 64) {
        int ei = base + t;
        if (ei < cnt) {
            int e = active[ei];
            sRC[t] = rcut[e];
            sI[t] = idx_i[e];
            sJ[t] = idx_j[e];
        } else {
            sRC[t] = 0.0f; sI[t] = 0; sJ[t] = 0;
        }
    }

    // stage A: f_ij tile (RBF + edge_emb), bf16
    {
        int e_loc = t >> 2;
        int r0 = (t & 3) * 8;
        int ei = base + e_loc;
        short v[8];
        if (ei < cnt) {
            int e = active[ei];
            float d = d_ij[e];
            const float* em = edge_emb + edge_attr[e] * NR + r0;
#pragma unroll
            for (int j = 0; j < 8; j++) {
                float off = (float)(r0 + j) * RBF_STEP;
                float dd = d - off;
                v[j] = f2bs(__expf(RBF_COEFF * dd * dd) + em[j]);
            }
        } else {
#pragma unroll
            for (int j = 0; j < 8; j++) v[j] = 0;
        }
        *(bf16x8*)&fA[e_loc * EPAD + r0] = *(bf16x8*)v;
    }
    __syncthreads();

    int wid = t >> 6, lane = t & 63;
    int quad = lane >> 4, col = lane & 15;
    int mrow = wid * 16 + col;

    // GEMM1: hidden = f_ij @ W1  (K=32, one MFMA per tile)
    {
        bf16x8 a1 = *(bf16x8*)&fA[mrow * EPAD + quad * 8];
        f32x4 acc[8];
#pragma unroll
        for (int nt = 0; nt < 8; nt++) {
            bf16x8 b = *(const bf16x8*)&W1T[(nt * 16 + col) * NR + quad * 8];
            acc[nt] = __builtin_amdgcn_mfma_f32_16x16x32_bf16(a1, b, (f32x4){0.f, 0.f, 0.f, 0.f}, 0, 0, 0);
        }
#pragma unroll
        for (int nt = 0; nt < 8; nt++) {
            int n = nt * 16 + col;
            float bias = b1[n];
#pragma unroll
            for (int r = 0; r < 4; r++) {
                int m = wid * 16 + quad * 4 + r;
                H[m * HPAD + n] = f2bs(ssp_f(acc[nt][r] + bias));
            }
        }
    }
    __syncthreads();

    // GEMM2: Wij = hidden @ W2  (K=128)
    f32x4 acc2[8] = {};
#pragma unroll
    for (int kt = 0; kt < 4; kt++) {
        bf16x8 a = *(bf16x8*)&H[mrow * HPAD + kt * 32 + quad * 8];
#pragma unroll
        for (int nt = 0; nt < 8; nt++) {
            bf16x8 b = *(const bf16x8*)&W2T[(nt * 16 + col) * NB + kt * 32 + quad * 8];
            acc2[nt] = __builtin_amdgcn_mfma_f32_16x16x32_bf16(a, b, acc2[nt], 0, 0, 0);
        }
    }

    // epilogue: *rcut, gather xf[idx_j], scatter-add agg[idx_i]
#pragma unroll
    for (int nt = 0; nt < 8; nt++) {
        int n = nt * 16 + col;
        float bias = b2[n];
#pragma unroll
        for (int r = 0; r < 4; r++) {
            int e_loc = wid * 16 + quad * 4 + r;
            float rc = sRC[e_loc];
            if (rc > 0.0f) {
                float w = (acc2[nt][r] + bias) * rc;
                float xv = xf[(size_t)sJ[e_loc] * NB + n];
                atomicAdd(&agg[(size_t)sI[e_loc] * NB + n], w * xv);
            }
        }
    }
}

// ---------------------------------------------------------------------------
// Head: L2-normalize, silu->W1->silu->W2, segment-sum into out[batch].
// ---------------------------------------------------------------------------
__global__ __launch_bounds__(128) void head_k(const float* __restrict__ x,
                                              const int* __restrict__ batch,
                                              const float* __restrict__ W1,
                                              const float* __restrict__ b1,
                                              const float* __restrict__ W2,
                                              float* __restrict__ out, int N) {
    int a0 = blockIdx.x * 8;
    int f = threadIdx.x;
    __shared__ float rows[8][NB];
    __shared__ float red[NB][9];
    __shared__ float srow[8][NB];
#pragma unroll
    for (int a = 0; a < 8; a++) {
        int n = a0 + a;
        rows[a][f] = (n < N) ? x[n * NB + f] : 0.0f;
    }
    __syncthreads();
#pragma unroll
    for (int a = 0; a < 8; a++) red[f][a] = rows[a][f] * rows[a][f];
    __syncthreads();
    for (int s = 64; s >= 1; s >>= 1) {
        if (f < s) {
#pragma unroll
            for (int a = 0; a < 8; a++) red[f][a] += red[f + s][a];
        }
        __syncthreads();
    }
    float nrm[8];
#pragma unroll
    for (int a = 0; a < 8; a++) nrm[a] = fmaxf(sqrtf(red[0][a]), 1e-12f);
#pragma unroll
    for (int a = 0; a < 8; a++) {
        float hv = rows[a][f] / nrm[a];
        srow[a][f] = silu_f(hv);
    }
    __syncthreads();
    float acc[8];
    float bb = b1[f];
#pragma unroll
    for (int a = 0; a < 8; a++) acc[a] = bb;
    for (int k4 = 0; k4 < 32; k4++) {
        float w0 = W1[(4 * k4 + 0) * NB + f];
        float w1 = W1[(4 * k4 + 1) * NB + f];
        float w2 = W1[(4 * k4 + 2) * NB + f];
        float w3 = W1[(4 * k4 + 3) * NB + f];
#pragma unroll
        for (int a = 0; a < 8; a++) {
            float4 r = *(const float4*)&srow[a][4 * k4];
            acc[a] += r.x * w0 + r.y * w1 + r.z * w2 + r.w * w3;
        }
    }
    float w2v = W2[f];
#pragma unroll
    for (int a = 0; a < 8; a++) red[f][a] = silu_f(acc[a]) * w2v;
    __syncthreads();
    for (int s = 64; s >= 1; s >>= 1) {
        if (f < s) {
#pragma unroll
            for (int a = 0; a < 8; a++) red[f][a] += red[f + s][a];
        }
        __syncthreads();
    }
    if (f == 0) {
#pragma unroll
        for (int a = 0; a < 8; a++) {
            int n = a0 + a;
            if (n < N) atomicAdd(&out[batch[n]], red[0][a]);
        }
    }
}

// ---------------------------------------------------------------------------
extern "C" void kernel_launch(void* const* d_in, const int* in_sizes, int n_in,
                              void* d_out, int out_size, void* d_ws, size_t ws_size,
                              hipStream_t stream) {
    const int*   z        = (const int*)d_in[0];
    const int*   z_res    = (const int*)d_in[1];
    const float* pos      = (const float*)d_in[2];
    const int*   idx_i    = (const int*)d_in[3];
    const int*   idx_j    = (const int*)d_in[4];
    const int*   edge_attr= (const int*)d_in[5];
    const int*   batch    = (const int*)d_in[6];
    const float* ele_emb  = (const float*)d_in[7];
    const float* res_emb  = (const float*)d_in[8];
    const float* edge_emb = (const float*)d_in[9];
    const float* in2f_W   = (const float*)d_in[10];
    const float* filt_W1  = (const float*)d_in[11];
    const float* filt_b1  = (const float*)d_in[12];
    const float* filt_W2  = (const float*)d_in[13];
    const float* filt_b2  = (const float*)d_in[14];
    const float* f2out_W1 = (const float*)d_in[15];
    const float* f2out_b1 = (const float*)d_in[16];
    const float* f2out_W2 = (const float*)d_in[17];
    const float* f2out_b2 = (const float*)d_in[18];
    const float* head_W1  = (const float*)d_in[19];
    const float* head_b1  = (const float*)d_in[20];
    const float* head_W2  = (const float*)d_in[21];

    const int N = in_sizes[0];
    const int E = in_sizes[3];

    char* p = (char*)d_ws;
    size_t off = 0;
    auto carve = [&](size_t bytes) -> void* {
        void* q = p + off;
        off = (off + bytes + 255) & ~(size_t)255;
        return q;
    };
    float* d_d      = (float*)carve((size_t)E * 4);
    float* d_rc     = (float*)carve((size_t)E * 4);
    int*   active   = (int*)carve((size_t)E * 4);
    int*   count    = (int*)carve(256);
    float* x_buf    = (float*)carve((size_t)N * NB * 4);
    float* xf_buf   = (float*)carve((size_t)N * NB * 4);
    float* agg      = (float*)carve((size_t)N * NB * 4);
    short* in2f_WT  = (short*)carve((size_t)6 * NB * NB * 2);
    short* fW1T     = (short*)carve((size_t)6 * NR * NB * 2);
    short* fW2T     = (short*)carve((size_t)6 * NB * NB * 2);
    short* oW1T     = (short*)carve((size_t)6 * NB * NB * 2);
    short* oW2T     = (short*)carve((size_t)6 * NB * NB * 2);
    (void)ws_size;

    // weight prep (bf16 transposed)
    {
        int tot = 6 * NB * NB;
        transpose_cvt<<<(tot + 255) / 256, 256, 0, stream>>>(in2f_W, in2f_WT, NB, NB, tot);
        transpose_cvt<<<(tot + 255) / 256, 256, 0, stream>>>(filt_W2, fW2T, NB, NB, tot);
        transpose_cvt<<<(tot + 255) / 256, 256, 0, stream>>>(f2out_W1, oW1T, NB, NB, tot);
        transpose_cvt<<<(tot + 255) / 256, 256, 0, stream>>>(f2out_W2, oW2T, NB, NB, tot);
        int tot1 = 6 * NR * NB;
        transpose_cvt<<<(tot1 + 255) / 256, 256, 0, stream>>>(filt_W1, fW1T, NR, NB, tot1);
    }

    hipMemsetAsync(count, 0, sizeof(int), stream);
    edge_prep<<<(E + 255) / 256, 256, 0, stream>>>(pos, idx_i, idx_j, d_d, d_rc, active, count, E);
    atom_embed<<<(N * NB + 255) / 256, 256, 0, stream>>>(z, z_res, ele_emb, res_emb, x_buf, N);

    int nblk_atom64 = (N + 63) / 64;
    int nblk_edge = (E + 63) / 64;
    for (int i = 0; i < 6; i++) {
        node_in2f_mfma<<<nblk_atom64, 256, 0, stream>>>(x_buf, in2f_WT + (size_t)i * NB * NB,
                                                        xf_buf, N);
        hipMemsetAsync(agg, 0, (size_t)N * NB * 4, stream);
        edge_fused_mfma<<<nblk_edge, 256, 0, stream>>>(
            d_d, d_rc, active, count, idx_i, idx_j, edge_attr, edge_emb,
            fW1T + (size_t)i * NR * NB, filt_b1 + (size_t)i * NB,
            fW2T + (size_t)i * NB * NB, filt_b2 + (size_t)i * NB,
            xf_buf, agg);
        node_out_mfma<<<nblk_atom64, 256, 0, stream>>>(
            agg, oW1T + (size_t)i * NB * NB, f2out_b1 + (size_t)i * NB,
            oW2T + (size_t)i * NB * NB, f2out_b2 + (size_t)i * NB, x_buf, N);
    }

    hipMemsetAsync(d_out, 0, (size_t)out_size * sizeof(float), stream);
    head_k<<<(N + 7) / 8, 128, 0, stream>>>(x_buf, batch, head_W1, head_b1, head_W2,
                                            (float*)d_out, N);
}

// Round 3
// 3408.067 us; speedup vs baseline: 5.6889x; 1.3510x over previous
//
#include <hip/hip_runtime.h>
#include <hip/hip_bf16.h>
#include <math.h>

#define NB 128
#define NR 32
#define EPAD 40    // fA row stride in shorts
#define HPAD 136   // H/XA row stride in shorts
#define XPAD 132   // head fp32 row stride in floats

static constexpr float CUTOFF_F    = 10.0f;
static constexpr float RBF_STEP    = 10.0f / 31.0f;
static constexpr float RBF_COEFF   = -4.805f;           // -0.5/(10/31)^2
static constexpr float LOG2_F      = 0.69314718055994531f;
static constexpr float PI_OVER_CUT = 0.314159265358979f;

typedef __attribute__((ext_vector_type(8))) short bf16x8;
typedef __attribute__((ext_vector_type(4))) float f32x4;

__device__ __forceinline__ short f2bs(float x) {
    __hip_bfloat16 h = __float2bfloat16(x);   // RNE
    return *reinterpret_cast<short*>(&h);
}
__device__ __forceinline__ float ssp_f(float v) {
    return fmaxf(v, 0.0f) + __logf(1.0f + __expf(-fabsf(v))) - LOG2_F;
}
__device__ __forceinline__ float silu_f(float v) {
    return v / (1.0f + __expf(-v));
}

// ---------------------------------------------------------------------------
// Weight prep: dst[b][c][r] = bf16(src[b][r][c])
// ---------------------------------------------------------------------------
__global__ void transpose_cvt(const float* __restrict__ src, short* __restrict__ dst,
                              int R, int C, int total) {
    int t = blockIdx.x * blockDim.x + threadIdx.x;
    if (t >= total) return;
    int rc = R * C;
    int b = t / rc;
    int rem = t - b * rc;
    int c = rem / R;
    int r = rem - c * R;
    dst[t] = f2bs(src[(size_t)b * rc + (size_t)r * C + c]);
}

// ---------------------------------------------------------------------------
// Edge prep: d, rcut, active count, and per-atom histogram of idx_i.
// ---------------------------------------------------------------------------
__global__ void edge_prep2(const float* __restrict__ pos,
                           const int* __restrict__ idx_i,
                           const int* __restrict__ idx_j,
                           float* __restrict__ d_ij,
                           float* __restrict__ rcut,
                           int* __restrict__ hist,
                           int* __restrict__ count,
                           int E) {
    int e = blockIdx.x * blockDim.x + threadIdx.x;
    if (e >= E) return;
    int a = idx_i[e], b = idx_j[e];
    float dx = pos[a * 3 + 0] - pos[b * 3 + 0];
    float dy = pos[a * 3 + 1] - pos[b * 3 + 1];
    float dz = pos[a * 3 + 2] - pos[b * 3 + 2];
    float d = sqrtf(dx * dx + dy * dy + dz * dz);
    d_ij[e] = d;
    float rc = 0.0f;
    bool act = (d < CUTOFF_F);
    if (act) rc = 0.5f * (cosf(d * PI_OVER_CUT) + 1.0f);
    rcut[e] = rc;
    if (act) {
        atomicAdd(&hist[a], 1);
        atomicAdd(count, 1);
    }
}

// ---------------------------------------------------------------------------
// Single-block exclusive scan of hist[N] -> cursor[N]  (1024 threads).
// ---------------------------------------------------------------------------
__global__ __launch_bounds__(1024) void scan_hist(const int* __restrict__ hist,
                                                  int* __restrict__ cursor, int N) {
    __shared__ int part[1024];
    int t = threadIdx.x;
    int chunk = (N + 1023) / 1024;
    int lo = t * chunk;
    int hi = min(lo + chunk, N);
    int s = 0;
    for (int i = lo; i < hi; i++) s += hist[i];
    part[t] = s;
    __syncthreads();
    for (int d = 1; d < 1024; d <<= 1) {
        int v = (t >= d) ? part[t - d] : 0;
        __syncthreads();
        part[t] += v;
        __syncthreads();
    }
    int run = (t == 0) ? 0 : part[t - 1];
    for (int i = lo; i < hi; i++) {
        cursor[i] = run;
        run += hist[i];
    }
}

// ---------------------------------------------------------------------------
// Scatter active edges into idx_i-grouped order.
// ---------------------------------------------------------------------------
__global__ void scatter_sorted(const float* __restrict__ d_ij,
                               const int* __restrict__ idx_i,
                               int* __restrict__ cursor,
                               int* __restrict__ sorted, int E) {
    int e = blockIdx.x * blockDim.x + threadIdx.x;
    if (e >= E) return;
    if (d_ij[e] < CUTOFF_F) {
        int p = atomicAdd(&cursor[idx_i[e]], 1);
        sorted[p] = e;
    }
}

// ---------------------------------------------------------------------------
// x = ele_emb[z] + res_emb[z_res]
// ---------------------------------------------------------------------------
__global__ void atom_embed(const int* __restrict__ z,
                           const int* __restrict__ z_res,
                           const float* __restrict__ ele_emb,
                           const float* __restrict__ res_emb,
                           float* __restrict__ x, int N) {
    int t = blockIdx.x * blockDim.x + threadIdx.x;
    if (t >= N * NB) return;
    int n = t >> 7, c = t & 127;
    x[t] = ele_emb[z[n] * NB + c] + res_emb[z_res[n] * NB + c];
}

// ---------------------------------------------------------------------------
// out[64xNB] = in[64xNB] @ W  via MFMA. First-iteration in2f.
// ---------------------------------------------------------------------------
__global__ __launch_bounds__(256, 4) void node_in2f_mfma(
    const float* __restrict__ x, const short* __restrict__ WT,
    float* __restrict__ out, int N) {
    __shared__ __align__(16) short XA[64 * HPAD];
    int a0 = blockIdx.x * 64;
    int t = threadIdx.x;
#pragma unroll
    for (int c = 0; c < 4; c++) {
        int chunk = t + c * 256;
        int row = chunk >> 4;
        int col = (chunk & 15) * 8;
        short v[8];
        if (a0 + row < N) {
            const float* src = x + (size_t)(a0 + row) * NB + col;
            float4 f0 = *(const float4*)src;
            float4 f1 = *(const float4*)(src + 4);
            v[0] = f2bs(f0.x); v[1] = f2bs(f0.y); v[2] = f2bs(f0.z); v[3] = f2bs(f0.w);
            v[4] = f2bs(f1.x); v[5] = f2bs(f1.y); v[6] = f2bs(f1.z); v[7] = f2bs(f1.w);
        } else {
#pragma unroll
            for (int j = 0; j < 8; j++) v[j] = 0;
        }
        *(bf16x8*)&XA[row * HPAD + col] = *(bf16x8*)v;
    }
    __syncthreads();

    int wid = t >> 6, lane = t & 63;
    int quad = lane >> 4, col = lane & 15;
    int mrow = wid * 16 + col;

    f32x4 acc[8] = {};
#pragma unroll
    for (int kt = 0; kt < 4; kt++) {
        bf16x8 a = *(bf16x8*)&XA[mrow * HPAD + kt * 32 + quad * 8];
#pragma unroll
        for (int nt = 0; nt < 8; nt++) {
            bf16x8 b = *(const bf16x8*)&WT[(nt * 16 + col) * NB + kt * 32 + quad * 8];
            acc[nt] = __builtin_amdgcn_mfma_f32_16x16x32_bf16(a, b, acc[nt], 0, 0, 0);
        }
    }
#pragma unroll
    for (int nt = 0; nt < 8; nt++) {
        int n = nt * 16 + col;
#pragma unroll
        for (int r = 0; r < 4; r++) {
            int m = wid * 16 + quad * 4 + r;
            if (a0 + m < N) out[(size_t)(a0 + m) * NB + n] = acc[nt][r];
        }
    }
}

// ---------------------------------------------------------------------------
// Fused: v = ssp(agg@W1+b1)@W2+b2 ; x += v ; xf_next = x @ Wn  (3 GEMMs)
// ---------------------------------------------------------------------------
__global__ __launch_bounds__(256, 4) void node_fused_mfma(
    const float* __restrict__ agg,
    const short* __restrict__ W1T, const float* __restrict__ b1,
    const short* __restrict__ W2T, const float* __restrict__ b2,
    const short* __restrict__ WnT,
    float* __restrict__ x, float* __restrict__ xf, int N) {
    __shared__ __align__(16) short XA[64 * HPAD];
    __shared__ __align__(16) short H[64 * HPAD];
    int a0 = blockIdx.x * 64;
    int t = threadIdx.x;
#pragma unroll
    for (int c = 0; c < 4; c++) {
        int chunk = t + c * 256;
        int row = chunk >> 4;
        int col = (chunk & 15) * 8;
        short v[8];
        if (a0 + row < N) {
            const float* src = agg + (size_t)(a0 + row) * NB + col;
            float4 f0 = *(const float4*)src;
            float4 f1 = *(const float4*)(src + 4);
            v[0] = f2bs(f0.x); v[1] = f2bs(f0.y); v[2] = f2bs(f0.z); v[3] = f2bs(f0.w);
            v[4] = f2bs(f1.x); v[5] = f2bs(f1.y); v[6] = f2bs(f1.z); v[7] = f2bs(f1.w);
        } else {
#pragma unroll
            for (int j = 0; j < 8; j++) v[j] = 0;
        }
        *(bf16x8*)&XA[row * HPAD + col] = *(bf16x8*)v;
    }
    __syncthreads();

    int wid = t >> 6, lane = t & 63;
    int quad = lane >> 4, col = lane & 15;
    int mrow = wid * 16 + col;

    // GEMM1 + ssp -> H
    {
        f32x4 acc[8] = {};
#pragma unroll
        for (int kt = 0; kt < 4; kt++) {
            bf16x8 a = *(bf16x8*)&XA[mrow * HPAD + kt * 32 + quad * 8];
#pragma unroll
            for (int nt = 0; nt < 8; nt++) {
                bf16x8 b = *(const bf16x8*)&W1T[(nt * 16 + col) * NB + kt * 32 + quad * 8];
                acc[nt] = __builtin_amdgcn_mfma_f32_16x16x32_bf16(a, b, acc[nt], 0, 0, 0);
            }
        }
#pragma unroll
        for (int nt = 0; nt < 8; nt++) {
            int n = nt * 16 + col;
            float bias = b1[n];
#pragma unroll
            for (int r = 0; r < 4; r++) {
                int m = wid * 16 + quad * 4 + r;
                H[m * HPAD + n] = f2bs(ssp_f(acc[nt][r] + bias));
            }
        }
    }
    __syncthreads();   // all GEMM1 done: XA is dead from here

    // GEMM2 + residual: x_new -> global fp32 + XA bf16 (reuse)
    {
        f32x4 acc[8] = {};
#pragma unroll
        for (int kt = 0; kt < 4; kt++) {
            bf16x8 a = *(bf16x8*)&H[mrow * HPAD + kt * 32 + quad * 8];
#pragma unroll
            for (int nt = 0; nt < 8; nt++) {
                bf16x8 b = *(const bf16x8*)&W2T[(nt * 16 + col) * NB + kt * 32 + quad * 8];
                acc[nt] = __builtin_amdgcn_mfma_f32_16x16x32_bf16(a, b, acc[nt], 0, 0, 0);
            }
        }
#pragma unroll
        for (int nt = 0; nt < 8; nt++) {
            int n = nt * 16 + col;
            float bias = b2[n];
#pragma unroll
            for (int r = 0; r < 4; r++) {
                int m = wid * 16 + quad * 4 + r;
                float xn = 0.0f;
                if (a0 + m < N) {
                    size_t o = (size_t)(a0 + m) * NB + n;
                    xn = x[o] + acc[nt][r] + bias;
                    x[o] = xn;
                }
                XA[m * HPAD + n] = f2bs(xn);
            }
        }
    }
    __syncthreads();

    // GEMM3: xf = x_new @ Wn
    {
        f32x4 acc[8] = {};
#pragma unroll
        for (int kt = 0; kt < 4; kt++) {
            bf16x8 a = *(bf16x8*)&XA[mrow * HPAD + kt * 32 + quad * 8];
#pragma unroll
            for (int nt = 0; nt < 8; nt++) {
                bf16x8 b = *(const bf16x8*)&WnT[(nt * 16 + col) * NB + kt * 32 + quad * 8];
                acc[nt] = __builtin_amdgcn_mfma_f32_16x16x32_bf16(a, b, acc[nt], 0, 0, 0);
            }
        }
#pragma unroll
        for (int nt = 0; nt < 8; nt++) {
            int n = nt * 16 + col;
#pragma unroll
            for (int r = 0; r < 4; r++) {
                int m = wid * 16 + quad * 4 + r;
                if (a0 + m < N) xf[(size_t)(a0 + m) * NB + n] = acc[nt][r];
            }
        }
    }
}

// ---------------------------------------------------------------------------
// Last iteration: x += ssp(agg @ W1 + b1) @ W2 + b2   (2 GEMMs)
// ---------------------------------------------------------------------------
__global__ __launch_bounds__(256, 4) void node_out_mfma(
    const float* __restrict__ agg,
    const short* __restrict__ W1T, const float* __restrict__ b1,
    const short* __restrict__ W2T, const float* __restrict__ b2,
    float* __restrict__ x, int N) {
    __shared__ __align__(16) short XA[64 * HPAD];
    __shared__ __align__(16) short H[64 * HPAD];
    int a0 = blockIdx.x * 64;
    int t = threadIdx.x;
#pragma unroll
    for (int c = 0; c < 4; c++) {
        int chunk = t + c * 256;
        int row = chunk >> 4;
        int col = (chunk & 15) * 8;
        short v[8];
        if (a0 + row < N) {
            const float* src = agg + (size_t)(a0 + row) * NB + col;
            float4 f0 = *(const float4*)src;
            float4 f1 = *(const float4*)(src + 4);
            v[0] = f2bs(f0.x); v[1] = f2bs(f0.y); v[2] = f2bs(f0.z); v[3] = f2bs(f0.w);
            v[4] = f2bs(f1.x); v[5] = f2bs(f1.y); v[6] = f2bs(f1.z); v[7] = f2bs(f1.w);
        } else {
#pragma unroll
            for (int j = 0; j < 8; j++) v[j] = 0;
        }
        *(bf16x8*)&XA[row * HPAD + col] = *(bf16x8*)v;
    }
    __syncthreads();

    int wid = t >> 6, lane = t & 63;
    int quad = lane >> 4, col = lane & 15;
    int mrow = wid * 16 + col;

    {
        f32x4 acc[8] = {};
#pragma unroll
        for (int kt = 0; kt < 4; kt++) {
            bf16x8 a = *(bf16x8*)&XA[mrow * HPAD + kt * 32 + quad * 8];
#pragma unroll
            for (int nt = 0; nt < 8; nt++) {
                bf16x8 b = *(const bf16x8*)&W1T[(nt * 16 + col) * NB + kt * 32 + quad * 8];
                acc[nt] = __builtin_amdgcn_mfma_f32_16x16x32_bf16(a, b, acc[nt], 0, 0, 0);
            }
        }
#pragma unroll
        for (int nt = 0; nt < 8; nt++) {
            int n = nt * 16 + col;
            float bias = b1[n];
#pragma unroll
            for (int r = 0; r < 4; r++) {
                int m = wid * 16 + quad * 4 + r;
                H[m * HPAD + n] = f2bs(ssp_f(acc[nt][r] + bias));
            }
        }
    }
    __syncthreads();
    {
        f32x4 acc[8] = {};
#pragma unroll
        for (int kt = 0; kt < 4; kt++) {
            bf16x8 a = *(bf16x8*)&H[mrow * HPAD + kt * 32 + quad * 8];
#pragma unroll
            for (int nt = 0; nt < 8; nt++) {
                bf16x8 b = *(const bf16x8*)&W2T[(nt * 16 + col) * NB + kt * 32 + quad * 8];
                acc[nt] = __builtin_amdgcn_mfma_f32_16x16x32_bf16(a, b, acc[nt], 0, 0, 0);
            }
        }
#pragma unroll
        for (int nt = 0; nt < 8; nt++) {
            int n = nt * 16 + col;
            float bias = b2[n];
#pragma unroll
            for (int r = 0; r < 4; r++) {
                int m = wid * 16 + quad * 4 + r;
                if (a0 + m < N) {
                    size_t o = (size_t)(a0 + m) * NB + n;
                    x[o] += acc[nt][r] + bias;
                }
            }
        }
    }
}

// ---------------------------------------------------------------------------
// Fused edge filter (MFMA) + gather + merged scatter. 64 sorted edges/block.
// Edges grouped by idx_i -> register-merge consecutive equal-i atomics.
// ---------------------------------------------------------------------------
__global__ __launch_bounds__(256, 4) void edge_fused_mfma(
    const float* __restrict__ d_ij, const float* __restrict__ rcut,
    const int* __restrict__ sorted, const int* __restrict__ count,
    const int* __restrict__ idx_i, const int* __restrict__ idx_j,
    const int* __restrict__ edge_attr, const float* __restrict__ edge_emb,
    const short* __restrict__ W1T, const float* __restrict__ b1,
    const short* __restrict__ W2T, const float* __restrict__ b2,
    const float* __restrict__ xf, float* __restrict__ agg) {
    __shared__ __align__(16) short fA[64 * EPAD];
    __shared__ __align__(16) short H[64 * HPAD];
    __shared__ float sRC[64];
    __shared__ int sI[64], sJ[64];

    int cnt = *count;
    int base = blockIdx.x * 64;
    if (base >= cnt) return;
    int t = threadIdx.x;

    if (t < 64) {
        int ei = base + t;
        if (ei < cnt) {
            int e = sorted[ei];
            sRC[t] = rcut[e];
            sI[t] = idx_i[e];
            sJ[t] = idx_j[e];
        } else {
            sRC[t] = 0.0f; sI[t] = 0; sJ[t] = 0;
        }
    }

    {
        int e_loc = t >> 2;
        int r0 = (t & 3) * 8;
        int ei = base + e_loc;
        short v[8];
        if (ei < cnt) {
            int e = sorted[ei];
            float d = d_ij[e];
            const float* em = edge_emb + edge_attr[e] * NR + r0;
#pragma unroll
            for (int j = 0; j < 8; j++) {
                float off = (float)(r0 + j) * RBF_STEP;
                float dd = d - off;
                v[j] = f2bs(__expf(RBF_COEFF * dd * dd) + em[j]);
            }
        } else {
#pragma unroll
            for (int j = 0; j < 8; j++) v[j] = 0;
        }
        *(bf16x8*)&fA[e_loc * EPAD + r0] = *(bf16x8*)v;
    }
    __syncthreads();

    int wid = t >> 6, lane = t & 63;
    int quad = lane >> 4, col = lane & 15;
    int mrow = wid * 16 + col;

    // GEMM1: hidden = f_ij @ W1 (K=32)
    {
        bf16x8 a1 = *(bf16x8*)&fA[mrow * EPAD + quad * 8];
        f32x4 acc[8];
#pragma unroll
        for (int nt = 0; nt < 8; nt++) {
            bf16x8 b = *(const bf16x8*)&W1T[(nt * 16 + col) * NR + quad * 8];
            acc[nt] = __builtin_amdgcn_mfma_f32_16x16x32_bf16(a1, b, (f32x4){0.f, 0.f, 0.f, 0.f}, 0, 0, 0);
        }
#pragma unroll
        for (int nt = 0; nt < 8; nt++) {
            int n = nt * 16 + col;
            float bias = b1[n];
#pragma unroll
            for (int r = 0; r < 4; r++) {
                int m = wid * 16 + quad * 4 + r;
                H[m * HPAD + n] = f2bs(ssp_f(acc[nt][r] + bias));
            }
        }
    }
    __syncthreads();

    // GEMM2: Wij = hidden @ W2 (K=128)
    f32x4 acc2[8] = {};
#pragma unroll
    for (int kt = 0; kt < 4; kt++) {
        bf16x8 a = *(bf16x8*)&H[mrow * HPAD + kt * 32 + quad * 8];
#pragma unroll
        for (int nt = 0; nt < 8; nt++) {
            bf16x8 b = *(const bf16x8*)&W2T[(nt * 16 + col) * NB + kt * 32 + quad * 8];
            acc2[nt] = __builtin_amdgcn_mfma_f32_16x16x32_bf16(a, b, acc2[nt], 0, 0, 0);
        }
    }

    // epilogue: gather xf[idx_j], merge equal-i runs, scatter-add agg[idx_i]
    int e0 = wid * 16 + quad * 4;
#pragma unroll
    for (int nt = 0; nt < 8; nt++) {
        int n = nt * 16 + col;
        float bias = b2[n];
        int cur = sI[e0];
        float accum = 0.0f;
#pragma unroll
        for (int r = 0; r < 4; r++) {
            int el = e0 + r;
            float w = (acc2[nt][r] + bias) * sRC[el];
            float xv = xf[(size_t)sJ[el] * NB + n];
            int ii = sI[el];
            if (ii != cur) {
                atomicAdd(&agg[(size_t)cur * NB + n], accum);
                accum = 0.0f;
                cur = ii;
            }
            accum = fmaf(w, xv, accum);
        }
        atomicAdd(&agg[(size_t)cur * NB + n], accum);
    }
}

// ---------------------------------------------------------------------------
// Head (MFMA): L2-normalize, silu -> W1 -> silu -> W2, segment-sum by batch.
// 64 rows / 256 threads per block.
// ---------------------------------------------------------------------------
__global__ __launch_bounds__(256, 4) void head_mfma(
    const float* __restrict__ x, const int* __restrict__ batch,
    const short* __restrict__ W1T, const float* __restrict__ b1,
    const float* __restrict__ W2,
    float* __restrict__ out, int N) {
    __shared__ float X[64 * XPAD];
    __shared__ __align__(16) short XA[64 * HPAD];
    __shared__ float invn[64];
    __shared__ int sbat[64];
    __shared__ float rowval[64];

    int a0 = blockIdx.x * 64;
    int t = threadIdx.x;

    // stage fp32 rows
#pragma unroll
    for (int c = 0; c < 8; c++) {
        int chunk = t + c * 256;       // 2048 float4 chunks
        int row = chunk >> 5;
        int col4 = (chunk & 31) * 4;
        float4 v;
        if (a0 + row < N) v = *(const float4*)(x + (size_t)(a0 + row) * NB + col4);
        else v = (float4){0.f, 0.f, 0.f, 0.f};
        *(float4*)&X[row * XPAD + col4] = v;
    }
    if (t < 64) sbat[t] = (a0 + t < N) ? batch[a0 + t] : -1;
    __syncthreads();

    // row 1/norm: 4 threads per row
    {
        int row = t >> 2, q = t & 3;
        const float* rp = &X[row * XPAD + q * 32];
        float s = 0.0f;
#pragma unroll
        for (int k4 = 0; k4 < 8; k4++) {
            float4 v = *(const float4*)(rp + k4 * 4);
            s += v.x * v.x + v.y * v.y + v.z * v.z + v.w * v.w;
        }
        s += __shfl_xor(s, 1);
        s += __shfl_xor(s, 2);
        if (q == 0) invn[row] = 1.0f / fmaxf(sqrtf(s), 1e-12f);
    }
    __syncthreads();

    // silu(x/norm) -> bf16 tile
    {
        int row = t >> 2, q = t & 3;
        float iv = invn[row];
        const float* rp = &X[row * XPAD + q * 32];
        short* wp = &XA[row * HPAD + q * 32];
#pragma unroll
        for (int k = 0; k < 32; k++) wp[k] = f2bs(silu_f(rp[k] * iv));
    }
    __syncthreads();

    int wid = t >> 6, lane = t & 63;
    int quad = lane >> 4, col = lane & 15;
    int mrow = wid * 16 + col;

    f32x4 acc[8] = {};
#pragma unroll
    for (int kt = 0; kt < 4; kt++) {
        bf16x8 a = *(bf16x8*)&XA[mrow * HPAD + kt * 32 + quad * 8];
#pragma unroll
        for (int nt = 0; nt < 8; nt++) {
            bf16x8 b = *(const bf16x8*)&W1T[(nt * 16 + col) * NB + kt * 32 + quad * 8];
            acc[nt] = __builtin_amdgcn_mfma_f32_16x16x32_bf16(a, b, acc[nt], 0, 0, 0);
        }
    }
    float partial[4] = {0.f, 0.f, 0.f, 0.f};
#pragma unroll
    for (int nt = 0; nt < 8; nt++) {
        int n = nt * 16 + col;
        float bias = b1[n];
        float w2 = W2[n];
#pragma unroll
        for (int r = 0; r < 4; r++) partial[r] += silu_f(acc[nt][r] + bias) * w2;
    }
#pragma unroll
    for (int r = 0; r < 4; r++) {
#pragma unroll
        for (int d = 1; d < 16; d <<= 1) partial[r] += __shfl_xor(partial[r], d);
    }
    if (col == 0) {
#pragma unroll
        for (int r = 0; r < 4; r++) rowval[wid * 16 + quad * 4 + r] = partial[r];
    }
    __syncthreads();

    // per-block segment-sum by batch id (batch is sorted)
    if (t < 64) {
        int b = sbat[t];
        bool valid = (b >= 0);
        bool headf = valid && (t == 0 || sbat[t - 1] != b);
        if (headf) {
            float s = 0.0f;
            int rr = t;
            while (rr < 64 && sbat[rr] == b) { s += rowval[rr]; rr++; }
            atomicAdd(&out[b], s);
        }
    }
}

// ---------------------------------------------------------------------------
extern "C" void kernel_launch(void* const* d_in, const int* in_sizes, int n_in,
                              void* d_out, int out_size, void* d_ws, size_t ws_size,
                              hipStream_t stream) {
    const int*   z        = (const int*)d_in[0];
    const int*   z_res    = (const int*)d_in[1];
    const float* pos      = (const float*)d_in[2];
    const int*   idx_i    = (const int*)d_in[3];
    const int*   idx_j    = (const int*)d_in[4];
    const int*   edge_attr= (const int*)d_in[5];
    const int*   batch    = (const int*)d_in[6];
    const float* ele_emb  = (const float*)d_in[7];
    const float* res_emb  = (const float*)d_in[8];
    const float* edge_emb = (const float*)d_in[9];
    const float* in2f_W   = (const float*)d_in[10];
    const float* filt_W1  = (const float*)d_in[11];
    const float* filt_b1  = (const float*)d_in[12];
    const float* filt_W2  = (const float*)d_in[13];
    const float* filt_b2  = (const float*)d_in[14];
    const float* f2out_W1 = (const float*)d_in[15];
    const float* f2out_b1 = (const float*)d_in[16];
    const float* f2out_W2 = (const float*)d_in[17];
    const float* f2out_b2 = (const float*)d_in[18];
    const float* head_W1  = (const float*)d_in[19];
    const float* head_b1  = (const float*)d_in[20];
    const float* head_W2  = (const float*)d_in[21];

    const int N = in_sizes[0];
    const int E = in_sizes[3];

    char* p = (char*)d_ws;
    size_t off = 0;
    auto carve = [&](size_t bytes) -> void* {
        void* q = p + off;
        off = (off + bytes + 255) & ~(size_t)255;
        return q;
    };
    float* d_d      = (float*)carve((size_t)E * 4);
    float* d_rc     = (float*)carve((size_t)E * 4);
    int*   sorted   = (int*)carve((size_t)E * 4);
    int*   hist     = (int*)carve((size_t)N * 4);
    int*   cursor   = (int*)carve((size_t)N * 4);
    int*   count    = (int*)carve(256);
    float* x_buf    = (float*)carve((size_t)N * NB * 4);
    float* xf_buf   = (float*)carve((size_t)N * NB * 4);
    float* agg      = (float*)carve((size_t)N * NB * 4);
    short* in2f_WT  = (short*)carve((size_t)6 * NB * NB * 2);
    short* fW1T     = (short*)carve((size_t)6 * NR * NB * 2);
    short* fW2T     = (short*)carve((size_t)6 * NB * NB * 2);
    short* oW1T     = (short*)carve((size_t)6 * NB * NB * 2);
    short* oW2T     = (short*)carve((size_t)6 * NB * NB * 2);
    short* hW1T     = (short*)carve((size_t)NB * NB * 2);
    (void)ws_size;

    // weight prep (bf16 transposed)
    {
        int tot = 6 * NB * NB;
        transpose_cvt<<<(tot + 255) / 256, 256, 0, stream>>>(in2f_W, in2f_WT, NB, NB, tot);
        transpose_cvt<<<(tot + 255) / 256, 256, 0, stream>>>(filt_W2, fW2T, NB, NB, tot);
        transpose_cvt<<<(tot + 255) / 256, 256, 0, stream>>>(f2out_W1, oW1T, NB, NB, tot);
        transpose_cvt<<<(tot + 255) / 256, 256, 0, stream>>>(f2out_W2, oW2T, NB, NB, tot);
        int tot1 = 6 * NR * NB;
        transpose_cvt<<<(tot1 + 255) / 256, 256, 0, stream>>>(filt_W1, fW1T, NR, NB, tot1);
        int tot2 = NB * NB;
        transpose_cvt<<<(tot2 + 255) / 256, 256, 0, stream>>>(head_W1, hW1T, NB, NB, tot2);
    }

    // edge prep + idx_i-grouped sort
    hipMemsetAsync(hist, 0, (size_t)N * 4, stream);
    hipMemsetAsync(count, 0, sizeof(int), stream);
    edge_prep2<<<(E + 255) / 256, 256, 0, stream>>>(pos, idx_i, idx_j, d_d, d_rc,
                                                    hist, count, E);
    scan_hist<<<1, 1024, 0, stream>>>(hist, cursor, N);
    scatter_sorted<<<(E + 255) / 256, 256, 0, stream>>>(d_d, idx_i, cursor, sorted, E);

    atom_embed<<<(N * NB + 255) / 256, 256, 0, stream>>>(z, z_res, ele_emb, res_emb, x_buf, N);

    int nblk_atom64 = (N + 63) / 64;
    int nblk_edge = (E + 63) / 64;

    node_in2f_mfma<<<nblk_atom64, 256, 0, stream>>>(x_buf, in2f_WT, xf_buf, N);
    for (int i = 0; i < 6; i++) {
        hipMemsetAsync(agg, 0, (size_t)N * NB * 4, stream);
        edge_fused_mfma<<<nblk_edge, 256, 0, stream>>>(
            d_d, d_rc, sorted, count, idx_i, idx_j, edge_attr, edge_emb,
            fW1T + (size_t)i * NR * NB, filt_b1 + (size_t)i * NB,
            fW2T + (size_t)i * NB * NB, filt_b2 + (size_t)i * NB,
            xf_buf, agg);
        if (i < 5) {
            node_fused_mfma<<<nblk_atom64, 256, 0, stream>>>(
                agg, oW1T + (size_t)i * NB * NB, f2out_b1 + (size_t)i * NB,
                oW2T + (size_t)i * NB * NB, f2out_b2 + (size_t)i * NB,
                in2f_WT + (size_t)(i + 1) * NB * NB,
                x_buf, xf_buf, N);
        } else {
            node_out_mfma<<<nblk_atom64, 256, 0, stream>>>(
                agg, oW1T + (size_t)i * NB * NB, f2out_b1 + (size_t)i * NB,
                oW2T + (size_t)i * NB * NB, f2out_b2 + (size_t)i * NB, x_buf, N);
        }
    }

    hipMemsetAsync(d_out, 0, (size_t)out_size * sizeof(float), stream);
    head_mfma<<<nblk_atom64, 256, 0, stream>>>(x_buf, batch, hW1T, head_b1, head_W2,
                                               (float*)d_out, N);
}

// Round 4
// 3206.915 us; speedup vs baseline: 6.0457x; 1.0627x over previous
//
#include <hip/hip_runtime.h>
#include <hip/hip_bf16.h>
#include <math.h>

#define NB 128
#define NR 32
#define EPAD 40    // fA row stride in shorts
#define HPAD 136   // H/XA row stride in shorts
#define XPAD 132   // head fp32 row stride in floats

static constexpr float CUTOFF_F    = 10.0f;
static constexpr float RBF_STEP    = 10.0f / 31.0f;
static constexpr float RBF_COEFF   = -4.805f;           // -0.5/(10/31)^2
static constexpr float LOG2_F      = 0.69314718055994531f;
static constexpr float PI_OVER_CUT = 0.314159265358979f;

typedef __attribute__((ext_vector_type(8))) short bf16x8;
typedef __attribute__((ext_vector_type(4))) float f32x4;

__device__ __forceinline__ short f2bs(float x) {
    __hip_bfloat16 h = __float2bfloat16(x);   // RNE
    return *reinterpret_cast<short*>(&h);
}
__device__ __forceinline__ float bs2f(unsigned short u) {
    unsigned int v = ((unsigned int)u) << 16;
    return __uint_as_float(v);
}
__device__ __forceinline__ float ssp_f(float v) {
    return fmaxf(v, 0.0f) + __logf(1.0f + __expf(-fabsf(v))) - LOG2_F;
}
__device__ __forceinline__ float silu_f(float v) {
    return v / (1.0f + __expf(-v));
}

// ---------------------------------------------------------------------------
// Weight prep: dst[b][c][r] = bf16(src[b][r][c])
// ---------------------------------------------------------------------------
__global__ void transpose_cvt(const float* __restrict__ src, short* __restrict__ dst,
                              int R, int C, int total) {
    int t = blockIdx.x * blockDim.x + threadIdx.x;
    if (t >= total) return;
    int rc = R * C;
    int b = t / rc;
    int rem = t - b * rc;
    int c = rem / R;
    int r = rem - c * R;
    dst[t] = f2bs(src[(size_t)b * rc + (size_t)r * C + c]);
}

// ---------------------------------------------------------------------------
// Edge prep: d, rcut, per-atom histogram of idx_i (active only), count.
// ---------------------------------------------------------------------------
__global__ void edge_prep2(const float* __restrict__ pos,
                           const int* __restrict__ idx_i,
                           const int* __restrict__ idx_j,
                           float* __restrict__ d_ij,
                           float* __restrict__ rcut,
                           int* __restrict__ hist,
                           int* __restrict__ count,
                           int E) {
    int e = blockIdx.x * blockDim.x + threadIdx.x;
    if (e >= E) return;
    int a = idx_i[e], b = idx_j[e];
    float dx = pos[a * 3 + 0] - pos[b * 3 + 0];
    float dy = pos[a * 3 + 1] - pos[b * 3 + 1];
    float dz = pos[a * 3 + 2] - pos[b * 3 + 2];
    float d = sqrtf(dx * dx + dy * dy + dz * dz);
    d_ij[e] = d;
    float rc = 0.0f;
    bool act = (d < CUTOFF_F);
    if (act) rc = 0.5f * (cosf(d * PI_OVER_CUT) + 1.0f);
    rcut[e] = rc;
    if (act) {
        atomicAdd(&hist[a], 1);
        atomicAdd(count, 1);
    }
}

// ---------------------------------------------------------------------------
// Single-block exclusive scan of hist[N] -> cursor[N]  (1024 threads).
// ---------------------------------------------------------------------------
__global__ __launch_bounds__(1024) void scan_hist(const int* __restrict__ hist,
                                                  int* __restrict__ cursor, int N) {
    __shared__ int part[1024];
    int t = threadIdx.x;
    int chunk = (N + 1023) / 1024;
    int lo = t * chunk;
    int hi = min(lo + chunk, N);
    int s = 0;
    for (int i = lo; i < hi; i++) s += hist[i];
    part[t] = s;
    __syncthreads();
    for (int d = 1; d < 1024; d <<= 1) {
        int v = (t >= d) ? part[t - d] : 0;
        __syncthreads();
        part[t] += v;
        __syncthreads();
    }
    int run = (t == 0) ? 0 : part[t - 1];
    for (int i = lo; i < hi; i++) {
        cursor[i] = run;
        run += hist[i];
    }
}

// ---------------------------------------------------------------------------
// Scatter active edges into idx_i-grouped order, materializing packed
// per-edge records: edata[p] = {d, rc, j, attr}; sIarr[p] = i.
// ---------------------------------------------------------------------------
__global__ void scatter_sorted2(const float* __restrict__ d_ij,
                                const float* __restrict__ rcut,
                                const int* __restrict__ idx_i,
                                const int* __restrict__ idx_j,
                                const int* __restrict__ edge_attr,
                                int* __restrict__ cursor,
                                float4* __restrict__ edata,
                                int* __restrict__ sIarr, int E) {
    int e = blockIdx.x * blockDim.x + threadIdx.x;
    if (e >= E) return;
    float d = d_ij[e];
    if (d < CUTOFF_F) {
        int i = idx_i[e];
        int p = atomicAdd(&cursor[i], 1);
        float4 v;
        v.x = d;
        v.y = rcut[e];
        v.z = __int_as_float(idx_j[e]);
        v.w = __int_as_float(edge_attr[e]);
        edata[p] = v;
        sIarr[p] = i;
    }
}

// ---------------------------------------------------------------------------
// x = ele_emb[z] + res_emb[z_res]
// ---------------------------------------------------------------------------
__global__ void atom_embed(const int* __restrict__ z,
                           const int* __restrict__ z_res,
                           const float* __restrict__ ele_emb,
                           const float* __restrict__ res_emb,
                           float* __restrict__ x, int N) {
    int t = blockIdx.x * blockDim.x + threadIdx.x;
    if (t >= N * NB) return;
    int n = t >> 7, c = t & 127;
    x[t] = ele_emb[z[n] * NB + c] + res_emb[z_res[n] * NB + c];
}

// ---------------------------------------------------------------------------
// xf(bf16) = in(fp32) @ W  via MFMA. First-iteration in2f.
// ---------------------------------------------------------------------------
__global__ __launch_bounds__(256, 4) void node_in2f_mfma(
    const float* __restrict__ x, const short* __restrict__ WT,
    short* __restrict__ xf, int N) {
    __shared__ __align__(16) short XA[64 * HPAD];
    int a0 = blockIdx.x * 64;
    int t = threadIdx.x;
#pragma unroll
    for (int c = 0; c < 4; c++) {
        int chunk = t + c * 256;
        int row = chunk >> 4;
        int col = (chunk & 15) * 8;
        short v[8];
        if (a0 + row < N) {
            const float* src = x + (size_t)(a0 + row) * NB + col;
            float4 f0 = *(const float4*)src;
            float4 f1 = *(const float4*)(src + 4);
            v[0] = f2bs(f0.x); v[1] = f2bs(f0.y); v[2] = f2bs(f0.z); v[3] = f2bs(f0.w);
            v[4] = f2bs(f1.x); v[5] = f2bs(f1.y); v[6] = f2bs(f1.z); v[7] = f2bs(f1.w);
        } else {
#pragma unroll
            for (int j = 0; j < 8; j++) v[j] = 0;
        }
        *(bf16x8*)&XA[row * HPAD + col] = *(bf16x8*)v;
    }
    __syncthreads();

    int wid = t >> 6, lane = t & 63;
    int quad = lane >> 4, col = lane & 15;
    int mrow = wid * 16 + col;

    f32x4 acc[8] = {};
#pragma unroll
    for (int kt = 0; kt < 4; kt++) {
        bf16x8 a = *(bf16x8*)&XA[mrow * HPAD + kt * 32 + quad * 8];
#pragma unroll
        for (int nt = 0; nt < 8; nt++) {
            bf16x8 b = *(const bf16x8*)&WT[(nt * 16 + col) * NB + kt * 32 + quad * 8];
            acc[nt] = __builtin_amdgcn_mfma_f32_16x16x32_bf16(a, b, acc[nt], 0, 0, 0);
        }
    }
#pragma unroll
    for (int nt = 0; nt < 8; nt++) {
        int n = nt * 16 + col;
#pragma unroll
        for (int r = 0; r < 4; r++) {
            int m = wid * 16 + quad * 4 + r;
            if (a0 + m < N) xf[(size_t)(a0 + m) * NB + n] = f2bs(acc[nt][r]);
        }
    }
}

// ---------------------------------------------------------------------------
// Fused: v = ssp(agg@W1+b1)@W2+b2 ; x += v ; xf_next(bf16) = x @ Wn
// ---------------------------------------------------------------------------
__global__ __launch_bounds__(256, 4) void node_fused_mfma(
    const float* __restrict__ agg,
    const short* __restrict__ W1T, const float* __restrict__ b1,
    const short* __restrict__ W2T, const float* __restrict__ b2,
    const short* __restrict__ WnT,
    float* __restrict__ x, short* __restrict__ xf, int N) {
    __shared__ __align__(16) short XA[64 * HPAD];
    __shared__ __align__(16) short H[64 * HPAD];
    int a0 = blockIdx.x * 64;
    int t = threadIdx.x;
#pragma unroll
    for (int c = 0; c < 4; c++) {
        int chunk = t + c * 256;
        int row = chunk >> 4;
        int col = (chunk & 15) * 8;
        short v[8];
        if (a0 + row < N) {
            const float* src = agg + (size_t)(a0 + row) * NB + col;
            float4 f0 = *(const float4*)src;
            float4 f1 = *(const float4*)(src + 4);
            v[0] = f2bs(f0.x); v[1] = f2bs(f0.y); v[2] = f2bs(f0.z); v[3] = f2bs(f0.w);
            v[4] = f2bs(f1.x); v[5] = f2bs(f1.y); v[6] = f2bs(f1.z); v[7] = f2bs(f1.w);
        } else {
#pragma unroll
            for (int j = 0; j < 8; j++) v[j] = 0;
        }
        *(bf16x8*)&XA[row * HPAD + col] = *(bf16x8*)v;
    }
    __syncthreads();

    int wid = t >> 6, lane = t & 63;
    int quad = lane >> 4, col = lane & 15;
    int mrow = wid * 16 + col;

    // GEMM1 + ssp -> H
    {
        f32x4 acc[8] = {};
#pragma unroll
        for (int kt = 0; kt < 4; kt++) {
            bf16x8 a = *(bf16x8*)&XA[mrow * HPAD + kt * 32 + quad * 8];
#pragma unroll
            for (int nt = 0; nt < 8; nt++) {
                bf16x8 b = *(const bf16x8*)&W1T[(nt * 16 + col) * NB + kt * 32 + quad * 8];
                acc[nt] = __builtin_amdgcn_mfma_f32_16x16x32_bf16(a, b, acc[nt], 0, 0, 0);
            }
        }
#pragma unroll
        for (int nt = 0; nt < 8; nt++) {
            int n = nt * 16 + col;
            float bias = b1[n];
#pragma unroll
            for (int r = 0; r < 4; r++) {
                int m = wid * 16 + quad * 4 + r;
                H[m * HPAD + n] = f2bs(ssp_f(acc[nt][r] + bias));
            }
        }
    }
    __syncthreads();

    // GEMM2 + residual: x_new -> global fp32 + XA bf16 (reuse)
    {
        f32x4 acc[8] = {};
#pragma unroll
        for (int kt = 0; kt < 4; kt++) {
            bf16x8 a = *(bf16x8*)&H[mrow * HPAD + kt * 32 + quad * 8];
#pragma unroll
            for (int nt = 0; nt < 8; nt++) {
                bf16x8 b = *(const bf16x8*)&W2T[(nt * 16 + col) * NB + kt * 32 + quad * 8];
                acc[nt] = __builtin_amdgcn_mfma_f32_16x16x32_bf16(a, b, acc[nt], 0, 0, 0);
            }
        }
#pragma unroll
        for (int nt = 0; nt < 8; nt++) {
            int n = nt * 16 + col;
            float bias = b2[n];
#pragma unroll
            for (int r = 0; r < 4; r++) {
                int m = wid * 16 + quad * 4 + r;
                float xn = 0.0f;
                if (a0 + m < N) {
                    size_t o = (size_t)(a0 + m) * NB + n;
                    xn = x[o] + acc[nt][r] + bias;
                    x[o] = xn;
                }
                XA[m * HPAD + n] = f2bs(xn);
            }
        }
    }
    __syncthreads();

    // GEMM3: xf = x_new @ Wn  (bf16 out)
    {
        f32x4 acc[8] = {};
#pragma unroll
        for (int kt = 0; kt < 4; kt++) {
            bf16x8 a = *(bf16x8*)&XA[mrow * HPAD + kt * 32 + quad * 8];
#pragma unroll
            for (int nt = 0; nt < 8; nt++) {
                bf16x8 b = *(const bf16x8*)&WnT[(nt * 16 + col) * NB + kt * 32 + quad * 8];
                acc[nt] = __builtin_amdgcn_mfma_f32_16x16x32_bf16(a, b, acc[nt], 0, 0, 0);
            }
        }
#pragma unroll
        for (int nt = 0; nt < 8; nt++) {
            int n = nt * 16 + col;
#pragma unroll
            for (int r = 0; r < 4; r++) {
                int m = wid * 16 + quad * 4 + r;
                if (a0 + m < N) xf[(size_t)(a0 + m) * NB + n] = f2bs(acc[nt][r]);
            }
        }
    }
}

// ---------------------------------------------------------------------------
// Last iteration: x += ssp(agg @ W1 + b1) @ W2 + b2
// ---------------------------------------------------------------------------
__global__ __launch_bounds__(256, 4) void node_out_mfma(
    const float* __restrict__ agg,
    const short* __restrict__ W1T, const float* __restrict__ b1,
    const short* __restrict__ W2T, const float* __restrict__ b2,
    float* __restrict__ x, int N) {
    __shared__ __align__(16) short XA[64 * HPAD];
    __shared__ __align__(16) short H[64 * HPAD];
    int a0 = blockIdx.x * 64;
    int t = threadIdx.x;
#pragma unroll
    for (int c = 0; c < 4; c++) {
        int chunk = t + c * 256;
        int row = chunk >> 4;
        int col = (chunk & 15) * 8;
        short v[8];
        if (a0 + row < N) {
            const float* src = agg + (size_t)(a0 + row) * NB + col;
            float4 f0 = *(const float4*)src;
            float4 f1 = *(const float4*)(src + 4);
            v[0] = f2bs(f0.x); v[1] = f2bs(f0.y); v[2] = f2bs(f0.z); v[3] = f2bs(f0.w);
            v[4] = f2bs(f1.x); v[5] = f2bs(f1.y); v[6] = f2bs(f1.z); v[7] = f2bs(f1.w);
        } else {
#pragma unroll
            for (int j = 0; j < 8; j++) v[j] = 0;
        }
        *(bf16x8*)&XA[row * HPAD + col] = *(bf16x8*)v;
    }
    __syncthreads();

    int wid = t >> 6, lane = t & 63;
    int quad = lane >> 4, col = lane & 15;
    int mrow = wid * 16 + col;

    {
        f32x4 acc[8] = {};
#pragma unroll
        for (int kt = 0; kt < 4; kt++) {
            bf16x8 a = *(bf16x8*)&XA[mrow * HPAD + kt * 32 + quad * 8];
#pragma unroll
            for (int nt = 0; nt < 8; nt++) {
                bf16x8 b = *(const bf16x8*)&W1T[(nt * 16 + col) * NB + kt * 32 + quad * 8];
                acc[nt] = __builtin_amdgcn_mfma_f32_16x16x32_bf16(a, b, acc[nt], 0, 0, 0);
            }
        }
#pragma unroll
        for (int nt = 0; nt < 8; nt++) {
            int n = nt * 16 + col;
            float bias = b1[n];
#pragma unroll
            for (int r = 0; r < 4; r++) {
                int m = wid * 16 + quad * 4 + r;
                H[m * HPAD + n] = f2bs(ssp_f(acc[nt][r] + bias));
            }
        }
    }
    __syncthreads();
    {
        f32x4 acc[8] = {};
#pragma unroll
        for (int kt = 0; kt < 4; kt++) {
            bf16x8 a = *(bf16x8*)&H[mrow * HPAD + kt * 32 + quad * 8];
#pragma unroll
            for (int nt = 0; nt < 8; nt++) {
                bf16x8 b = *(const bf16x8*)&W2T[(nt * 16 + col) * NB + kt * 32 + quad * 8];
                acc[nt] = __builtin_amdgcn_mfma_f32_16x16x32_bf16(a, b, acc[nt], 0, 0, 0);
            }
        }
#pragma unroll
        for (int nt = 0; nt < 8; nt++) {
            int n = nt * 16 + col;
            float bias = b2[n];
#pragma unroll
            for (int r = 0; r < 4; r++) {
                int m = wid * 16 + quad * 4 + r;
                if (a0 + m < N) {
                    size_t o = (size_t)(a0 + m) * NB + n;
                    x[o] += acc[nt][r] + bias;
                }
            }
        }
    }
}

// ---------------------------------------------------------------------------
// Fused edge filter (MFMA) + bf16 gather + merged scatter.
// 64 sorted edges/block; packed edata records (coalesced front-end).
// ---------------------------------------------------------------------------
__global__ __launch_bounds__(256, 4) void edge_fused_mfma(
    const float4* __restrict__ edata, const int* __restrict__ sIarr,
    const int* __restrict__ count,
    const float* __restrict__ edge_emb,
    const short* __restrict__ W1T, const float* __restrict__ b1,
    const short* __restrict__ W2T, const float* __restrict__ b2,
    const short* __restrict__ xf, float* __restrict__ agg) {
    __shared__ __align__(16) short fA[64 * EPAD];
    __shared__ __align__(16) short H[64 * HPAD];
    __shared__ float sD[64], sRC[64];
    __shared__ int sI[64], sJ[64], sA[64];

    int cnt = *count;
    int base = blockIdx.x * 64;
    if (base >= cnt) return;
    int t = threadIdx.x;

    if (t < 64) {
        int ei = base + t;
        if (ei < cnt) {
            float4 v = edata[ei];
            sD[t] = v.x;
            sRC[t] = v.y;
            sJ[t] = __float_as_int(v.z);
            sA[t] = __float_as_int(v.w);
            sI[t] = sIarr[ei];
        } else {
            sD[t] = 1e9f; sRC[t] = 0.0f; sJ[t] = 0; sA[t] = 0; sI[t] = 0;
        }
    }
    __syncthreads();

    // stage A: f_ij tile (RBF + edge_emb), bf16
    {
        int e_loc = t >> 2;
        int r0 = (t & 3) * 8;
        short v[8];
        if (base + e_loc < cnt) {
            float d = sD[e_loc];
            const float* em = edge_emb + sA[e_loc] * NR + r0;
#pragma unroll
            for (int j = 0; j < 8; j++) {
                float off = (float)(r0 + j) * RBF_STEP;
                float dd = d - off;
                v[j] = f2bs(__expf(RBF_COEFF * dd * dd) + em[j]);
            }
        } else {
#pragma unroll
            for (int j = 0; j < 8; j++) v[j] = 0;
        }
        *(bf16x8*)&fA[e_loc * EPAD + r0] = *(bf16x8*)v;
    }
    __syncthreads();

    int wid = t >> 6, lane = t & 63;
    int quad = lane >> 4, col = lane & 15;
    int mrow = wid * 16 + col;

    // GEMM1: hidden = f_ij @ W1 (K=32)
    {
        bf16x8 a1 = *(bf16x8*)&fA[mrow * EPAD + quad * 8];
        f32x4 acc[8];
#pragma unroll
        for (int nt = 0; nt < 8; nt++) {
            bf16x8 b = *(const bf16x8*)&W1T[(nt * 16 + col) * NR + quad * 8];
            acc[nt] = __builtin_amdgcn_mfma_f32_16x16x32_bf16(a1, b, (f32x4){0.f, 0.f, 0.f, 0.f}, 0, 0, 0);
        }
#pragma unroll
        for (int nt = 0; nt < 8; nt++) {
            int n = nt * 16 + col;
            float bias = b1[n];
#pragma unroll
            for (int r = 0; r < 4; r++) {
                int m = wid * 16 + quad * 4 + r;
                H[m * HPAD + n] = f2bs(ssp_f(acc[nt][r] + bias));
            }
        }
    }
    __syncthreads();

    // GEMM2: Wij = hidden @ W2 (K=128)
    f32x4 acc2[8] = {};
#pragma unroll
    for (int kt = 0; kt < 4; kt++) {
        bf16x8 a = *(bf16x8*)&H[mrow * HPAD + kt * 32 + quad * 8];
#pragma unroll
        for (int nt = 0; nt < 8; nt++) {
            bf16x8 b = *(const bf16x8*)&W2T[(nt * 16 + col) * NB + kt * 32 + quad * 8];
            acc2[nt] = __builtin_amdgcn_mfma_f32_16x16x32_bf16(a, b, acc2[nt], 0, 0, 0);
        }
    }

    // epilogue: bf16 gather xf[idx_j], merge equal-i runs, scatter agg[idx_i]
    int e0 = wid * 16 + quad * 4;
#pragma unroll
    for (int nt = 0; nt < 8; nt++) {
        int n = nt * 16 + col;
        float bias = b2[n];
        int cur = sI[e0];
        float accum = 0.0f;
#pragma unroll
        for (int r = 0; r < 4; r++) {
            int el = e0 + r;
            float w = (acc2[nt][r] + bias) * sRC[el];
            float xv = bs2f(((const unsigned short*)xf)[(size_t)sJ[el] * NB + n]);
            int ii = sI[el];
            if (ii != cur) {
                atomicAdd(&agg[(size_t)cur * NB + n], accum);
                accum = 0.0f;
                cur = ii;
            }
            accum = fmaf(w, xv, accum);
        }
        atomicAdd(&agg[(size_t)cur * NB + n], accum);
    }
}

// ---------------------------------------------------------------------------
// Head (MFMA): L2-normalize, silu -> W1 -> silu -> W2, segment-sum by batch.
// ---------------------------------------------------------------------------
__global__ __launch_bounds__(256, 4) void head_mfma(
    const float* __restrict__ x, const int* __restrict__ batch,
    const short* __restrict__ W1T, const float* __restrict__ b1,
    const float* __restrict__ W2,
    float* __restrict__ out, int N) {
    __shared__ float X[64 * XPAD];
    __shared__ __align__(16) short XA[64 * HPAD];
    __shared__ float invn[64];
    __shared__ int sbat[64];
    __shared__ float rowval[64];

    int a0 = blockIdx.x * 64;
    int t = threadIdx.x;

#pragma unroll
    for (int c = 0; c < 8; c++) {
        int chunk = t + c * 256;
        int row = chunk >> 5;
        int col4 = (chunk & 31) * 4;
        float4 v;
        if (a0 + row < N) v = *(const float4*)(x + (size_t)(a0 + row) * NB + col4);
        else v = (float4){0.f, 0.f, 0.f, 0.f};
        *(float4*)&X[row * XPAD + col4] = v;
    }
    if (t < 64) sbat[t] = (a0 + t < N) ? batch[a0 + t] : -1;
    __syncthreads();

    {
        int row = t >> 2, q = t & 3;
        const float* rp = &X[row * XPAD + q * 32];
        float s = 0.0f;
#pragma unroll
        for (int k4 = 0; k4 < 8; k4++) {
            float4 v = *(const float4*)(rp + k4 * 4);
            s += v.x * v.x + v.y * v.y + v.z * v.z + v.w * v.w;
        }
        s += __shfl_xor(s, 1);
        s += __shfl_xor(s, 2);
        if (q == 0) invn[row] = 1.0f / fmaxf(sqrtf(s), 1e-12f);
    }
    __syncthreads();

    {
        int row = t >> 2, q = t & 3;
        float iv = invn[row];
        const float* rp = &X[row * XPAD + q * 32];
        short* wp = &XA[row * HPAD + q * 32];
#pragma unroll
        for (int k = 0; k < 32; k++) wp[k] = f2bs(silu_f(rp[k] * iv));
    }
    __syncthreads();

    int wid = t >> 6, lane = t & 63;
    int quad = lane >> 4, col = lane & 15;
    int mrow = wid * 16 + col;

    f32x4 acc[8] = {};
#pragma unroll
    for (int kt = 0; kt < 4; kt++) {
        bf16x8 a = *(bf16x8*)&XA[mrow * HPAD + kt * 32 + quad * 8];
#pragma unroll
        for (int nt = 0; nt < 8; nt++) {
            bf16x8 b = *(const bf16x8*)&W1T[(nt * 16 + col) * NB + kt * 32 + quad * 8];
            acc[nt] = __builtin_amdgcn_mfma_f32_16x16x32_bf16(a, b, acc[nt], 0, 0, 0);
        }
    }
    float partial[4] = {0.f, 0.f, 0.f, 0.f};
#pragma unroll
    for (int nt = 0; nt < 8; nt++) {
        int n = nt * 16 + col;
        float bias = b1[n];
        float w2 = W2[n];
#pragma unroll
        for (int r = 0; r < 4; r++) partial[r] += silu_f(acc[nt][r] + bias) * w2;
    }
#pragma unroll
    for (int r = 0; r < 4; r++) {
#pragma unroll
        for (int d = 1; d < 16; d <<= 1) partial[r] += __shfl_xor(partial[r], d);
    }
    if (col == 0) {
#pragma unroll
        for (int r = 0; r < 4; r++) rowval[wid * 16 + quad * 4 + r] = partial[r];
    }
    __syncthreads();

    if (t < 64) {
        int b = sbat[t];
        bool valid = (b >= 0);
        bool headf = valid && (t == 0 || sbat[t - 1] != b);
        if (headf) {
            float s = 0.0f;
            int rr = t;
            while (rr < 64 && sbat[rr] == b) { s += rowval[rr]; rr++; }
            atomicAdd(&out[b], s);
        }
    }
}

// ---------------------------------------------------------------------------
extern "C" void kernel_launch(void* const* d_in, const int* in_sizes, int n_in,
                              void* d_out, int out_size, void* d_ws, size_t ws_size,
                              hipStream_t stream) {
    const int*   z        = (const int*)d_in[0];
    const int*   z_res    = (const int*)d_in[1];
    const float* pos      = (const float*)d_in[2];
    const int*   idx_i    = (const int*)d_in[3];
    const int*   idx_j    = (const int*)d_in[4];
    const int*   edge_attr= (const int*)d_in[5];
    const int*   batch    = (const int*)d_in[6];
    const float* ele_emb  = (const float*)d_in[7];
    const float* res_emb  = (const float*)d_in[8];
    const float* edge_emb = (const float*)d_in[9];
    const float* in2f_W   = (const float*)d_in[10];
    const float* filt_W1  = (const float*)d_in[11];
    const float* filt_b1  = (const float*)d_in[12];
    const float* filt_W2  = (const float*)d_in[13];
    const float* filt_b2  = (const float*)d_in[14];
    const float* f2out_W1 = (const float*)d_in[15];
    const float* f2out_b1 = (const float*)d_in[16];
    const float* f2out_W2 = (const float*)d_in[17];
    const float* f2out_b2 = (const float*)d_in[18];
    const float* head_W1  = (const float*)d_in[19];
    const float* head_b1  = (const float*)d_in[20];
    const float* head_W2  = (const float*)d_in[21];

    const int N = in_sizes[0];
    const int E = in_sizes[3];

    char* p = (char*)d_ws;
    size_t off = 0;
    auto carve = [&](size_t bytes) -> void* {
        void* q = p + off;
        off = (off + bytes + 255) & ~(size_t)255;
        return q;
    };
    float*  d_d      = (float*)carve((size_t)E * 4);
    float*  d_rc     = (float*)carve((size_t)E * 4);
    float4* edata    = (float4*)carve((size_t)E * 16);
    int*    sIarr    = (int*)carve((size_t)E * 4);
    int*    hist     = (int*)carve((size_t)N * 4);
    int*    cursor   = (int*)carve((size_t)N * 4);
    int*    count    = (int*)carve(256);
    float*  x_buf    = (float*)carve((size_t)N * NB * 4);
    short*  xf_buf   = (short*)carve((size_t)N * NB * 2);
    float*  agg      = (float*)carve((size_t)N * NB * 4);
    short*  in2f_WT  = (short*)carve((size_t)6 * NB * NB * 2);
    short*  fW1T     = (short*)carve((size_t)6 * NR * NB * 2);
    short*  fW2T     = (short*)carve((size_t)6 * NB * NB * 2);
    short*  oW1T     = (short*)carve((size_t)6 * NB * NB * 2);
    short*  oW2T     = (short*)carve((size_t)6 * NB * NB * 2);
    short*  hW1T     = (short*)carve((size_t)NB * NB * 2);
    (void)ws_size;

    // weight prep (bf16 transposed)
    {
        int tot = 6 * NB * NB;
        transpose_cvt<<<(tot + 255) / 256, 256, 0, stream>>>(in2f_W, in2f_WT, NB, NB, tot);
        transpose_cvt<<<(tot + 255) / 256, 256, 0, stream>>>(filt_W2, fW2T, NB, NB, tot);
        transpose_cvt<<<(tot + 255) / 256, 256, 0, stream>>>(f2out_W1, oW1T, NB, NB, tot);
        transpose_cvt<<<(tot + 255) / 256, 256, 0, stream>>>(f2out_W2, oW2T, NB, NB, tot);
        int tot1 = 6 * NR * NB;
        transpose_cvt<<<(tot1 + 255) / 256, 256, 0, stream>>>(filt_W1, fW1T, NR, NB, tot1);
        int tot2 = NB * NB;
        transpose_cvt<<<(tot2 + 255) / 256, 256, 0, stream>>>(head_W1, hW1T, NB, NB, tot2);
    }

    // edge prep + idx_i-grouped sort with packed records
    hipMemsetAsync(hist, 0, (size_t)N * 4, stream);
    hipMemsetAsync(count, 0, sizeof(int), stream);
    edge_prep2<<<(E + 255) / 256, 256, 0, stream>>>(pos, idx_i, idx_j, d_d, d_rc,
                                                    hist, count, E);
    scan_hist<<<1, 1024, 0, stream>>>(hist, cursor, N);
    scatter_sorted2<<<(E + 255) / 256, 256, 0, stream>>>(d_d, d_rc, idx_i, idx_j,
                                                         edge_attr, cursor, edata,
                                                         sIarr, E);

    atom_embed<<<(N * NB + 255) / 256, 256, 0, stream>>>(z, z_res, ele_emb, res_emb, x_buf, N);

    int nblk_atom64 = (N + 63) / 64;
    int nblk_edge = (E + 63) / 64;

    node_in2f_mfma<<<nblk_atom64, 256, 0, stream>>>(x_buf, in2f_WT, xf_buf, N);
    for (int i = 0; i < 6; i++) {
        hipMemsetAsync(agg, 0, (size_t)N * NB * 4, stream);
        edge_fused_mfma<<<nblk_edge, 256, 0, stream>>>(
            edata, sIarr, count, edge_emb,
            fW1T + (size_t)i * NR * NB, filt_b1 + (size_t)i * NB,
            fW2T + (size_t)i * NB * NB, filt_b2 + (size_t)i * NB,
            xf_buf, agg);
        if (i < 5) {
            node_fused_mfma<<<nblk_atom64, 256, 0, stream>>>(
                agg, oW1T + (size_t)i * NB * NB, f2out_b1 + (size_t)i * NB,
                oW2T + (size_t)i * NB * NB, f2out_b2 + (size_t)i * NB,
                in2f_WT + (size_t)(i + 1) * NB * NB,
                x_buf, xf_buf, N);
        } else {
            node_out_mfma<<<nblk_atom64, 256, 0, stream>>>(
                agg, oW1T + (size_t)i * NB * NB, f2out_b1 + (size_t)i * NB,
                oW2T + (size_t)i * NB * NB, f2out_b2 + (size_t)i * NB, x_buf, N);
        }
    }

    hipMemsetAsync(d_out, 0, (size_t)out_size * sizeof(float), stream);
    head_mfma<<<nblk_atom64, 256, 0, stream>>>(x_buf, batch, hW1T, head_b1, head_W2,
                                               (float*)d_out, N);
}